// Round 8
// baseline (3010.316 us; speedup 1.0000x reference)
//
#include <hip/hip_runtime.h>

// STA-LSTM forward. B=4096 S=16 D=256 HS=HT=512. Output y (B,1) fp32.
// R8: sa attention path fused into ONE kernel/step (A1 -> tanh -> A2 ->
//     softmax -> xt split, + piggyback X[:,t+1] split):
//       - BM=16 rows/block, grid 256 (all CUs), 256 thr.
//       - A/B MFMA fragments loaded DIRECTLY global->VGPR (weights are
//         L2-resident; no LDS staging, no per-chunk barriers -> compiler
//         pipelines loads freely). Only tmp (C->A layout xform) and av
//         (cross-wave softmax) go through LDS; 4 barriers/block total.
//       - accumulation order identical to R7 (same seg order, same 3-mfma
//         order per chunk) -> numerics unchanged except softmax sum order.
//     Kills 2 dispatches/step + 12 MB/step tmp/av HBM round-trips.
//   Gates (m97 plateau), beta, hctx, y, precision scheme unchanged.
// ws: ~176 MiB.

constexpr int Bb = 4096;
constexpr int Ss = 16;
constexpr int Dd = 256;
constexpr int Hh = 512;   // HS == HT

typedef __attribute__((ext_vector_type(8))) short short8;
typedef __attribute__((ext_vector_type(4))) float f32x4;

__device__ __forceinline__ float sigm(float x) { return 1.0f / (1.0f + expf(-x)); }

__device__ __forceinline__ unsigned short f2bf(float x) {   // RNE fp32->bf16 bits
    unsigned int u = __float_as_uint(x);
    u = (u + 0x7fffu + ((u >> 16) & 1u)) >> 16;
    return (unsigned short)u;
}
__device__ __forceinline__ float bf2f(unsigned short h) {
    return __uint_as_float(((unsigned int)h) << 16);
}
__device__ __forceinline__ void async16(const void* g, void* l) {
    __builtin_amdgcn_global_load_lds(
        (const __attribute__((address_space(1))) void*)g,
        (__attribute__((address_space(3))) void*)l, 16, 0, 0);
}
__device__ __forceinline__ short8 ldg8(const unsigned short* p) {
    return *reinterpret_cast<const short8*>(p);
}

struct SegB { const unsigned short* Ah; const unsigned short* Al;
              const unsigned short* Bh; const unsigned short* Bl;
              int lda; int ldb; int K; };

// ============ fused sa-attention: tmp=tanh(A1), av=tmp@Va, softmax, xt ====
// Block = 16 batch rows x full N=256. Frags straight from global (L2).
template<int NSEG, int SPLITX>
__global__ __launch_bounds__(256) void attn_fused_k(
    SegB s0, SegB s1, SegB s2,
    const unsigned short* __restrict__ VaTh, const unsigned short* __restrict__ VaTl,
    const float* __restrict__ saba,
    const float* __restrict__ X, int t,
    unsigned short* __restrict__ xth, unsigned short* __restrict__ xtl,
    unsigned short* __restrict__ xsh, unsigned short* __restrict__ xsl)
{
    __shared__ __align__(16) unsigned short tmpH[16 * 264];
    __shared__ __align__(16) unsigned short tmpL[16 * 264];
    __shared__ __align__(16) float av[16 * 260];
    __shared__ float rpart[16][16];
    __shared__ float spart[16][16];

    const int tid  = threadIdx.x;
    const int lane = tid & 63;
    const int wv   = tid >> 6;
    const int q8   = (lane >> 4) * 8;
    const int l15  = lane & 15;
    const int quad = lane >> 4;
    const int row0 = blockIdx.x * 16;

    // ---- stage 1: tmp = tanh(sum_seg A@B^T + ba) ----
    f32x4 acc[4];
#pragma unroll
    for (int j = 0; j < 4; j++) acc[j] = (f32x4){0.f, 0.f, 0.f, 0.f};

#pragma unroll
    for (int sgi = 0; sgi < NSEG; ++sgi) {
        const SegB sg = (sgi == 0) ? s0 : ((sgi == 1) ? s1 : s2);
        for (int k0 = 0; k0 < sg.K; k0 += 32) {
            const size_t aoff = (size_t)(row0 + l15) * sg.lda + k0 + q8;
            const short8 a_h = ldg8(sg.Ah + aoff);
            const short8 a_l = ldg8(sg.Al + aoff);
#pragma unroll
            for (int j = 0; j < 4; j++) {
                const int n = wv * 64 + j * 16 + l15;
                const size_t boff = (size_t)n * sg.ldb + k0 + q8;
                const short8 b_h = ldg8(sg.Bh + boff);
                const short8 b_l = ldg8(sg.Bl + boff);
                acc[j] = __builtin_amdgcn_mfma_f32_16x16x32_bf16(a_h, b_h, acc[j], 0, 0, 0);
                acc[j] = __builtin_amdgcn_mfma_f32_16x16x32_bf16(a_h, b_l, acc[j], 0, 0, 0);
                acc[j] = __builtin_amdgcn_mfma_f32_16x16x32_bf16(a_l, b_h, acc[j], 0, 0, 0);
            }
        }
    }
#pragma unroll
    for (int j = 0; j < 4; j++) {
        const int col = wv * 64 + j * 16 + l15;
        const float bb = saba[col];
#pragma unroll
        for (int r = 0; r < 4; r++) {
            const int rw = quad * 4 + r;
            const float v = tanhf(acc[j][r] + bb);
            const unsigned short hb = f2bf(v);
            tmpH[rw * 264 + col] = hb;
            tmpL[rw * 264 + col] = f2bf(v - bf2f(hb));
        }
    }
    __syncthreads();

    // ---- stage 2: av = tmp @ VaT^T ----
    f32x4 acc2[4];
#pragma unroll
    for (int j = 0; j < 4; j++) acc2[j] = (f32x4){0.f, 0.f, 0.f, 0.f};
#pragma unroll
    for (int kc = 0; kc < 8; ++kc) {
        const int k0 = kc * 32;
        const short8 a_h = *reinterpret_cast<const short8*>(&tmpH[l15 * 264 + k0 + q8]);
        const short8 a_l = *reinterpret_cast<const short8*>(&tmpL[l15 * 264 + k0 + q8]);
#pragma unroll
        for (int j = 0; j < 4; j++) {
            const int n = wv * 64 + j * 16 + l15;
            const size_t boff = (size_t)n * 256 + k0 + q8;
            const short8 b_h = ldg8(VaTh + boff);
            const short8 b_l = ldg8(VaTl + boff);
            acc2[j] = __builtin_amdgcn_mfma_f32_16x16x32_bf16(a_h, b_h, acc2[j], 0, 0, 0);
            acc2[j] = __builtin_amdgcn_mfma_f32_16x16x32_bf16(a_h, b_l, acc2[j], 0, 0, 0);
            acc2[j] = __builtin_amdgcn_mfma_f32_16x16x32_bf16(a_l, b_h, acc2[j], 0, 0, 0);
        }
    }
#pragma unroll
    for (int j = 0; j < 4; j++) {
        const int col = wv * 64 + j * 16 + l15;
#pragma unroll
        for (int r = 0; r < 4; r++) av[(quad * 4 + r) * 260 + col] = acc2[j][r];
    }
    __syncthreads();

    // ---- stage 3: softmax over D + scale by x_t (+ split X[:,t+1]) ----
    const int row = tid >> 4;
    const int sl  = tid & 15;
    const int c0  = sl * 16;
    float* avr = av + row * 260;
    float mx = avr[c0];
#pragma unroll
    for (int i = 1; i < 16; i++) mx = fmaxf(mx, avr[c0 + i]);
    rpart[row][sl] = mx;
    __syncthreads();
    float M = rpart[row][0];
#pragma unroll
    for (int i = 1; i < 16; i++) M = fmaxf(M, rpart[row][i]);
    float s = 0.0f;
#pragma unroll
    for (int i = 0; i < 16; i++) {
        const float e = expf(avr[c0 + i] - M);
        avr[c0 + i] = e;
        s += e;
    }
    spart[row][sl] = s;
    __syncthreads();
    float S = spart[row][0];
#pragma unroll
    for (int i = 1; i < 16; i++) S += spart[row][i];
    const float inv = 1.0f / S;

    const size_t b = (size_t)(row0 + row);
    const float* Xr = X + b * (Ss * Dd) + (size_t)t * Dd + c0;
    unsigned short* xhp = xth + b * Dd + c0;
    unsigned short* xlp = xtl + b * Dd + c0;
#pragma unroll
    for (int g = 0; g < 4; g++) {
        const float4 xv = *reinterpret_cast<const float4*>(Xr + g * 4);
        const float v0 = avr[c0 + g * 4 + 0] * inv * xv.x;
        const float v1 = avr[c0 + g * 4 + 1] * inv * xv.y;
        const float v2 = avr[c0 + g * 4 + 2] * inv * xv.z;
        const float v3 = avr[c0 + g * 4 + 3] * inv * xv.w;
        ushort4 ho, lo;
        ho.x = f2bf(v0); lo.x = f2bf(v0 - bf2f(ho.x));
        ho.y = f2bf(v1); lo.y = f2bf(v1 - bf2f(ho.y));
        ho.z = f2bf(v2); lo.z = f2bf(v2 - bf2f(ho.z));
        ho.w = f2bf(v3); lo.w = f2bf(v3 - bf2f(ho.w));
        *reinterpret_cast<ushort4*>(xhp + g * 4) = ho;
        *reinterpret_cast<ushort4*>(xlp + g * 4) = lo;
    }
    if (SPLITX) {
        const float* Xn = X + b * (Ss * Dd) + (size_t)(t + 1) * Dd + c0;
        unsigned short* shp = xsh + b * Dd + c0;
        unsigned short* slp = xsl + b * Dd + c0;
#pragma unroll
        for (int g = 0; g < 4; g++) {
            const float4 xv = *reinterpret_cast<const float4*>(Xn + g * 4);
            ushort4 ho, lo;
            ho.x = f2bf(xv.x); lo.x = f2bf(xv.x - bf2f(ho.x));
            ho.y = f2bf(xv.y); lo.y = f2bf(xv.y - bf2f(ho.y));
            ho.z = f2bf(xv.z); lo.z = f2bf(xv.z - bf2f(ho.z));
            ho.w = f2bf(xv.w); lo.w = f2bf(xv.w - bf2f(ho.w));
            *reinterpret_cast<ushort4*>(shp + g * 4) = ho;
            *reinterpret_cast<ushort4*>(slp + g * 4) = lo;
        }
    }
}

// ============ fused gates GEMM + LSTM pointwise (unchanged from R7) ========
template<int NSEG, int ZC, int TA>
__global__ __launch_bounds__(256) void gemm_gates_k(
    SegB s0, SegB s1,
    const float* __restrict__ bias,
    const float* __restrict__ wy,
    const float* __restrict__ yv,
    float* __restrict__ c_io,
    unsigned short* __restrict__ hh, unsigned short* __restrict__ hl,
    unsigned short* __restrict__ ch, unsigned short* __restrict__ cl)
{
    __shared__ __align__(16) unsigned short sA[2][128 * 32];
    __shared__ __align__(16) unsigned short sB[2][128 * 32];
    const int tid  = threadIdx.x;
    const int lane = tid & 63;
    const int wv   = tid >> 6;
    const int wm   = wv & 1, wn = wv >> 1;
    const int row0 = blockIdx.x * 128;
    const int by32 = blockIdx.y * 32;

    f32x4 acc[4][4];   // [m-tile][gate]
#pragma unroll
    for (int i = 0; i < 4; i++)
#pragma unroll
        for (int g = 0; g < 4; g++) acc[i][g] = (f32x4){0.f, 0.f, 0.f, 0.f};

    const int lrow = lane >> 2;
    const int lcol = (lane & 3) * 8;
    const int q8   = (lane >> 4) * 8;
    const int l15  = lane & 15;

#pragma unroll
    for (int sgi = 0; sgi < NSEG; ++sgi) {
        const SegB sg = (sgi == 0) ? s0 : s1;
        const int K = sg.K;
        for (int k0 = 0; k0 < K; k0 += 32) {
#pragma unroll
            for (int c = wv; c < 8; c += 4) {
                const int r = c * 16 + lrow;
                const size_t gA = (size_t)(row0 + r) * sg.lda + k0 + lcol;
                const int lo = c * 512 + lane * 8;
                async16(sg.Ah + gA, &sA[0][lo]);
                async16(sg.Al + gA, &sA[1][lo]);
            }
#pragma unroll
            for (int cc = wv; cc < 8; cc += 4) {
                const int g  = cc >> 1;
                const int jj = (cc & 1) * 16 + lrow;
                const int rowg = g * 512 + by32 + jj;
                const size_t gB = (size_t)rowg * sg.ldb + k0 + lcol;
                const int lo = cc * 512 + lane * 8;
                async16(sg.Bh + gB, &sB[0][lo]);
                async16(sg.Bl + gB, &sB[1][lo]);
            }
            __syncthreads();
            short8 ah[4], al[4], bh[4], bl[4];
#pragma unroll
            for (int i = 0; i < 4; i++) {
                const int m = wm * 64 + i * 16 + l15;
                ah[i] = *reinterpret_cast<const short8*>(&sA[0][m * 32 + q8]);
                al[i] = *reinterpret_cast<const short8*>(&sA[1][m * 32 + q8]);
            }
#pragma unroll
            for (int g = 0; g < 4; g++) {
                const int n = g * 32 + wn * 16 + l15;
                bh[g] = *reinterpret_cast<const short8*>(&sB[0][n * 32 + q8]);
                bl[g] = *reinterpret_cast<const short8*>(&sB[1][n * 32 + q8]);
            }
#pragma unroll
            for (int i = 0; i < 4; i++)
#pragma unroll
                for (int g = 0; g < 4; g++) {
                    acc[i][g] = __builtin_amdgcn_mfma_f32_16x16x32_bf16(ah[i], bh[g], acc[i][g], 0, 0, 0);
                    acc[i][g] = __builtin_amdgcn_mfma_f32_16x16x32_bf16(ah[i], bl[g], acc[i][g], 0, 0, 0);
                    acc[i][g] = __builtin_amdgcn_mfma_f32_16x16x32_bf16(al[i], bh[g], acc[i][g], 0, 0, 0);
                }
            __syncthreads();
        }
    }
    // ---- fused LSTM epilogue ----
    const int j = by32 + wn * 16 + l15;          // 0..511
    const float b0 = bias[j],            b1 = bias[Hh + j];
    const float b2 = bias[2 * Hh + j],   b3 = bias[3 * Hh + j];
    float w0 = 0.f, w1 = 0.f, w2 = 0.f, w3 = 0.f;
    if (TA) { w0 = wy[j]; w1 = wy[Hh + j]; w2 = wy[2 * Hh + j]; w3 = wy[3 * Hh + j]; }
#pragma unroll
    for (int i = 0; i < 4; i++) {
        const int rbase = row0 + wm * 64 + i * 16 + (lane >> 4) * 4;
#pragma unroll
        for (int r = 0; r < 4; r++) {
            const int row = rbase + r;
            float gi = acc[i][0][r] + b0;
            float gf = acc[i][1][r] + b1;
            float gg = acc[i][2][r] + b2;
            float go = acc[i][3][r] + b3;
            if (TA) {
                const float yb = yv[row];
                gi += yb * w0; gf += yb * w1; gg += yb * w2; go += yb * w3;
            }
            const float i_ = sigm(gi), f_ = sigm(gf), gv = tanhf(gg), o_ = sigm(go);
            const size_t idx = (size_t)row * Hh + j;
            const float cp = ZC ? 0.0f : c_io[idx];
            const float c = f_ * cp + i_ * gv;
            c_io[idx] = c;
            const float h = o_ * tanhf(c);
            const unsigned short hb = f2bf(h);
            hh[idx] = hb;
            hl[idx] = f2bf(h - bf2f(hb));
            if (!TA) {
                const unsigned short cb = f2bf(c);
                ch[idx] = cb;
                cl[idx] = f2bf(c - bf2f(cb));
            }
        }
    }
}

// ============ weight prep: W[K][N] fp32 -> Th,Tl [N][K] bf16 ============
__global__ __launch_bounds__(256) void splitT_k(const float* __restrict__ W,
                                                unsigned short* __restrict__ Th,
                                                unsigned short* __restrict__ Tl,
                                                int Kd, int Nd)
{
    __shared__ float tile[32][33];
    const int bk = blockIdx.x * 32, bn = blockIdx.y * 32;
    const int tid = threadIdx.x;
    const int r = tid >> 3, c4 = (tid & 7) * 4;
    const float4 v = *reinterpret_cast<const float4*>(&W[(size_t)(bk + r) * Nd + bn + c4]);
    tile[r][c4 + 0] = v.x; tile[r][c4 + 1] = v.y;
    tile[r][c4 + 2] = v.z; tile[r][c4 + 3] = v.w;
    __syncthreads();
    const int n = r, k4 = c4;
    ushort4 hq, lq;
    unsigned short* hp = (unsigned short*)&hq;
    unsigned short* lp = (unsigned short*)&lq;
#pragma unroll
    for (int q = 0; q < 4; q++) {
        float x = tile[k4 + q][n];
        unsigned short h = f2bf(x);
        hp[q] = h;
        lp[q] = f2bf(x - bf2f(h));
    }
    *reinterpret_cast<ushort4*>(&Th[(size_t)(bn + n) * Kd + bk + k4]) = hq;
    *reinterpret_cast<ushort4*>(&Tl[(size_t)(bn + n) * Kd + bk + k4]) = lq;
}

// ---- ta_Wa [512][16] -> WaT hi/lo [16][512] ----
__global__ __launch_bounds__(256) void splitWa_k(const float* __restrict__ W,
                                                 unsigned short* __restrict__ Th,
                                                 unsigned short* __restrict__ Tl)
{
    int idx = blockIdx.x * 256 + threadIdx.x;   // 8192
    int n = idx >> 9, k = idx & 511;
    float x = W[(size_t)k * 16 + n];
    unsigned short h = f2bf(x);
    Th[idx] = h;
    Tl[idx] = f2bf(x - bf2f(h));
}

// -------- init: y0 = X[:,0,255]; split X[:,0,:] --------
__global__ __launch_bounds__(256) void init_k(const float* __restrict__ X,
                                              unsigned short* __restrict__ xsh,
                                              unsigned short* __restrict__ xsl,
                                              float* __restrict__ yv)
{
    int idx = blockIdx.x * 256 + threadIdx.x;
    int b = idx >> 8, d = idx & 255;
    float xv = X[(size_t)b * (Ss * Dd) + d];
    unsigned short hb = f2bf(xv);
    xsh[idx] = hb;
    xsl[idx] = f2bf(xv - bf2f(hb));
    if (d == Dd - 1) yv[b] = xv;
}

// ------- beta: MFMA logits (65536x512 @ WaT 16x512) + fused tanh/@Va/softmax -------
__global__ __launch_bounds__(256) void beta_k(const unsigned short* __restrict__ H3h,
                                              const unsigned short* __restrict__ H3l,
                                              const unsigned short* __restrict__ WaTh,
                                              const unsigned short* __restrict__ WaTl,
                                              const float* __restrict__ taba,
                                              const float* __restrict__ taVa,
                                              float* __restrict__ beta)
{
    __shared__ __align__(16) unsigned short sW[2][16 * 512];   // 32 KB
    __shared__ __align__(16) unsigned short sA[2][128 * 32];   // 16 KB
    __shared__ float tt[128][17];                               // 8.5 KB
    __shared__ float Vas[256];
    const int tid  = threadIdx.x;
    const int lane = tid & 63;
    const int wv   = tid >> 6;
    const int lrow = lane >> 2;
    const int lcol = (lane & 3) * 8;
    const int q8   = (lane >> 4) * 8;
    const int l15  = lane & 15;
    const size_t row0 = (size_t)blockIdx.x * 128;

#pragma unroll
    for (int it = 0; it < 4; ++it) {
        const int lo = wv * 2048 + it * 512 + lane * 8;
        async16(WaTh + lo, &sW[0][lo]);
        async16(WaTl + lo, &sW[1][lo]);
    }
    Vas[tid] = taVa[tid];

    f32x4 acc[2];
    acc[0] = (f32x4){0.f, 0.f, 0.f, 0.f};
    acc[1] = (f32x4){0.f, 0.f, 0.f, 0.f};

    for (int kc = 0; kc < 16; ++kc) {
        const int k0 = kc * 32;
#pragma unroll
        for (int c = wv; c < 8; c += 4) {
            const int r = c * 16 + lrow;
            const size_t gA = (row0 + r) * Hh + k0 + lcol;
            const int lo = c * 512 + lane * 8;
            async16(H3h + gA, &sA[0][lo]);
            async16(H3l + gA, &sA[1][lo]);
        }
        __syncthreads();
        const short8 bh = *reinterpret_cast<const short8*>(&sW[0][l15 * 512 + k0 + q8]);
        const short8 bl = *reinterpret_cast<const short8*>(&sW[1][l15 * 512 + k0 + q8]);
#pragma unroll
        for (int i = 0; i < 2; i++) {
            const int m = wv * 32 + i * 16 + l15;
            const short8 ah = *reinterpret_cast<const short8*>(&sA[0][m * 32 + q8]);
            const short8 al = *reinterpret_cast<const short8*>(&sA[1][m * 32 + q8]);
            acc[i] = __builtin_amdgcn_mfma_f32_16x16x32_bf16(ah, bh, acc[i], 0, 0, 0);
            acc[i] = __builtin_amdgcn_mfma_f32_16x16x32_bf16(ah, bl, acc[i], 0, 0, 0);
            acc[i] = __builtin_amdgcn_mfma_f32_16x16x32_bf16(al, bh, acc[i], 0, 0, 0);
        }
        __syncthreads();
    }
    const float ba = taba[l15];
#pragma unroll
    for (int i = 0; i < 2; i++) {
#pragma unroll
        for (int r = 0; r < 4; r++) {
            const int rl = wv * 32 + i * 16 + (lane >> 4) * 4 + r;
            tt[rl][l15] = tanhf(acc[i][r] + ba);
        }
    }
    __syncthreads();
    if (tid < 128) {
        float tv[16];
#pragma unroll
        for (int m = 0; m < 16; m++) tv[m] = tt[tid][m];
        float l[16];
        float mx = -1e30f;
#pragma unroll
        for (int n = 0; n < 16; n++) {
            float s = 0.0f;
#pragma unroll
            for (int m = 0; m < 16; m++) s = fmaf(tv[m], Vas[m * 16 + n], s);
            l[n] = s;
            mx = fmaxf(mx, s);
        }
        float sum = 0.0f;
#pragma unroll
        for (int n = 0; n < 16; n++) { l[n] = expf(l[n] - mx); sum += l[n]; }
        const float inv = 1.0f / sum;
        float* bp = beta + (row0 + tid) * 16;
#pragma unroll
        for (int n4 = 0; n4 < 4; n4++) {
            float4 v = { l[n4 * 4] * inv, l[n4 * 4 + 1] * inv,
                         l[n4 * 4 + 2] * inv, l[n4 * 4 + 3] * inv };
            *reinterpret_cast<float4*>(bp + n4 * 4) = v;
        }
    }
}

// ------- h_ctx for ALL t in one dispatch, in-place into H3 (vectorized) -------
__global__ __launch_bounds__(256) void hctx_all_k(unsigned short* __restrict__ H3h,
                                                  unsigned short* __restrict__ H3l,
                                                  const float* __restrict__ beta)
{
    const int b = blockIdx.x, tid = threadIdx.x;
    __shared__ float4 Hs4[16][129];   // 16 s x 128 quads (+1 pad)
    __shared__ float bs[16][16];
    for (int i = tid; i < 16 * 128; i += 256) {
        const int s = i >> 7, q = i & 127;
        const size_t o = ((size_t)s * Bb + b) * Hh + q * 4;
        const ushort4 hv = *reinterpret_cast<const ushort4*>(&H3h[o]);
        const ushort4 lv = *reinterpret_cast<const ushort4*>(&H3l[o]);
        Hs4[s][q] = (float4){ bf2f(hv.x) + bf2f(lv.x), bf2f(hv.y) + bf2f(lv.y),
                              bf2f(hv.z) + bf2f(lv.z), bf2f(hv.w) + bf2f(lv.w) };
    }
    {
        const int t = tid >> 4, s = tid & 15;
        bs[t][s] = beta[((size_t)t * Bb + b) * 16 + s];
    }
    __syncthreads();
    const int q  = tid & 127;
    const int t0 = tid >> 7;          // 0 or 1
#pragma unroll
    for (int tt = 0; tt < 8; tt++) {
        const int t = tt * 2 + t0;
        float4 a = (float4){0.f, 0.f, 0.f, 0.f};
#pragma unroll
        for (int s = 0; s < 16; s++) {
            const float w = bs[t][s];
            const float4 hv = Hs4[s][q];
            a.x = fmaf(w, hv.x, a.x); a.y = fmaf(w, hv.y, a.y);
            a.z = fmaf(w, hv.z, a.z); a.w = fmaf(w, hv.w, a.w);
        }
        ushort4 ho, lo;
        ho.x = f2bf(a.x); lo.x = f2bf(a.x - bf2f(ho.x));
        ho.y = f2bf(a.y); lo.y = f2bf(a.y - bf2f(ho.y));
        ho.z = f2bf(a.z); lo.z = f2bf(a.z - bf2f(ho.z));
        ho.w = f2bf(a.w); lo.w = f2bf(a.w - bf2f(ho.w));
        const size_t o = ((size_t)t * Bb + b) * Hh + q * 4;
        *reinterpret_cast<ushort4*>(&H3h[o]) = ho;
        *reinterpret_cast<ushort4*>(&H3l[o]) = lo;
    }
}

// ---------------- y = lh @ fc_W.T + fc_b (lh from hi/lo) ----------------
__global__ __launch_bounds__(256) void y_k(const unsigned short* __restrict__ hh,
                                           const unsigned short* __restrict__ hl,
                                           const float* __restrict__ fcW,
                                           const float* __restrict__ fcb,
                                           float* __restrict__ yv,
                                           float* __restrict__ outp)
{
    int b = blockIdx.x, tid = threadIdx.x;
    size_t o = (size_t)b * Hh + tid;
    float h0 = bf2f(hh[o]) + bf2f(hl[o]);
    float h1 = bf2f(hh[o + 256]) + bf2f(hl[o + 256]);
    float p = h0 * fcW[tid] + h1 * fcW[tid + 256];
#pragma unroll
    for (int off = 32; off > 0; off >>= 1) p += __shfl_down(p, off, 64);
    __shared__ float wred[4];
    if ((tid & 63) == 0) wred[tid >> 6] = p;
    __syncthreads();
    if (tid == 0) {
        float y = fcb[0] + wred[0] + wred[1] + wred[2] + wred[3];
        yv[b] = y;
        if (outp) outp[b] = y;
    }
}

extern "C" void kernel_launch(void* const* d_in, const int* in_sizes, int n_in,
                              void* d_out, int out_size, void* d_ws, size_t ws_size,
                              hipStream_t stream)
{
    (void)in_sizes; (void)n_in; (void)out_size; (void)ws_size;
    const float* X     = (const float*)d_in[0];
    const float* sa_W  = (const float*)d_in[1];
    const float* sa_U  = (const float*)d_in[2];
    const float* sa_b  = (const float*)d_in[3];
    const float* sa_Wa = (const float*)d_in[4];
    const float* sa_Ua = (const float*)d_in[5];
    const float* sa_ba = (const float*)d_in[6];
    const float* sa_Va = (const float*)d_in[7];
    const float* ta_Wa = (const float*)d_in[8];
    // d_in[9] = ta_Ua : multiplied by s0 == 0 -> unused
    const float* ta_ba = (const float*)d_in[10];
    const float* ta_Va = (const float*)d_in[11];
    const float* ta_W  = (const float*)d_in[12];
    const float* ta_U  = (const float*)d_in[13];
    const float* ta_b  = (const float*)d_in[14];
    const float* ta_Wy = (const float*)d_in[15];
    const float* fc_W  = (const float*)d_in[16];
    const float* fc_b  = (const float*)d_in[17];

    char* base = (char*)d_ws;
    size_t off = 0;
    auto alloc = [&](size_t bytes) {
        void* p = base + off; off += (bytes + 255) & ~(size_t)255; return p;
    };
    const size_t BH = (size_t)Bb * Hh;          // 2M elems
    unsigned short* H3h = (unsigned short*)alloc((size_t)Ss * BH * 2);  // 64 MiB
    unsigned short* H3l = (unsigned short*)alloc((size_t)Ss * BH * 2);  // 64 MiB
    float* cbuf = (float*)alloc(BH * 4);         // 8 MiB (sa c fp32; ta: lhA alias)
    float* lc   = (float*)alloc(BH * 4);         // 8 MiB
    unsigned short* lhBh = (unsigned short*)alloc(BH * 2);              // 4 MiB
    unsigned short* lhBl = (unsigned short*)alloc(BH * 2);              // 4 MiB
    unsigned short* xth = (unsigned short*)alloc((size_t)Bb * Dd * 2);  // 2 MiB
    unsigned short* xtl = (unsigned short*)alloc((size_t)Bb * Dd * 2);  // 2 MiB
    unsigned short* xsh = (unsigned short*)alloc((size_t)Bb * Dd * 2);  // 2 MiB
    unsigned short* xsl = (unsigned short*)alloc((size_t)Bb * Dd * 2);  // 2 MiB
    unsigned short* ch  = (unsigned short*)alloc(BH * 2);               // 4 MiB
    unsigned short* cl  = (unsigned short*)alloc(BH * 2);               // 4 MiB
    unsigned short* saWth = (unsigned short*)alloc((size_t)Dd * 4 * Hh * 2);
    unsigned short* saWtl = (unsigned short*)alloc((size_t)Dd * 4 * Hh * 2);
    unsigned short* saUth = (unsigned short*)alloc((size_t)Hh * 4 * Hh * 2);
    unsigned short* saUtl = (unsigned short*)alloc((size_t)Hh * 4 * Hh * 2);
    unsigned short* taWth = (unsigned short*)alloc((size_t)Hh * 4 * Hh * 2);
    unsigned short* taWtl = (unsigned short*)alloc((size_t)Hh * 4 * Hh * 2);
    unsigned short* taUth = (unsigned short*)alloc((size_t)Hh * 4 * Hh * 2);
    unsigned short* taUtl = (unsigned short*)alloc((size_t)Hh * 4 * Hh * 2);
    unsigned short* WaTh = (unsigned short*)alloc((size_t)Dd * Dd * 2);
    unsigned short* WaTl = (unsigned short*)alloc((size_t)Dd * Dd * 2);
    unsigned short* UaTh = (unsigned short*)alloc((size_t)2 * Hh * Dd * 2);
    unsigned short* UaTl = (unsigned short*)alloc((size_t)2 * Hh * Dd * 2);
    unsigned short* VaTh = (unsigned short*)alloc((size_t)Dd * Dd * 2);
    unsigned short* VaTl = (unsigned short*)alloc((size_t)Dd * Dd * 2);
    unsigned short* tWaTh = (unsigned short*)alloc((size_t)16 * Hh * 2);
    unsigned short* tWaTl = (unsigned short*)alloc((size_t)16 * Hh * 2);
    float* yv = (float*)alloc((size_t)Bb * 4);
    // aliases (dead at time of reuse):
    float* beta = (float*)xth;                    // 4 MiB over xth+xtl (ta phase)
    unsigned short* lhAh = (unsigned short*)cbuf; // ta phase (cbuf dead)
    unsigned short* lhAl = (unsigned short*)cbuf + BH;
    unsigned short* lhh[2] = { lhAh, lhBh };
    unsigned short* lhl[2] = { lhAl, lhBl };
    // total ~176 MiB

    // ---- weight prep ----
    splitT_k<<<dim3(Dd / 32, (4 * Hh) / 32), 256, 0, stream>>>(sa_W, saWth, saWtl, Dd, 4 * Hh);
    splitT_k<<<dim3(Hh / 32, (4 * Hh) / 32), 256, 0, stream>>>(sa_U, saUth, saUtl, Hh, 4 * Hh);
    splitT_k<<<dim3(Hh / 32, (4 * Hh) / 32), 256, 0, stream>>>(ta_W, taWth, taWtl, Hh, 4 * Hh);
    splitT_k<<<dim3(Hh / 32, (4 * Hh) / 32), 256, 0, stream>>>(ta_U, taUth, taUtl, Hh, 4 * Hh);
    splitT_k<<<dim3(Dd / 32, Dd / 32), 256, 0, stream>>>(sa_Wa, WaTh, WaTl, Dd, Dd);
    splitT_k<<<dim3((2 * Hh) / 32, Dd / 32), 256, 0, stream>>>(sa_Ua, UaTh, UaTl, 2 * Hh, Dd);
    splitT_k<<<dim3(Dd / 32, Dd / 32), 256, 0, stream>>>(sa_Va, VaTh, VaTl, Dd, Dd);
    splitWa_k<<<dim3(32), 256, 0, stream>>>(ta_Wa, tWaTh, tWaTl);
    init_k<<<dim3((Bb * Dd) / 256), 256, 0, stream>>>(X, xsh, xsl, yv);

    const dim3 agrid(Bb / 16);                   // 256 blocks
    const dim3 ggrid(Bb / 128, Hh / 32);         // 32 x 16

    // ---- spatial-attention LSTM ----
    for (int t = 0; t < Ss; ++t) {
        // fused: tmp=tanh(x@Wa + h@Ua_h + c@Ua_c + ba); av=tmp@Va; softmax; xt
        SegB a0{ xsh, xsl, WaTh, WaTl, Dd, Dd, Dd };
        if (t == 0) {
            attn_fused_k<1, 1><<<agrid, 256, 0, stream>>>(
                a0, a0, a0, VaTh, VaTl, sa_ba, X, t, xth, xtl, xsh, xsl);
        } else {
            SegB a1{ H3h + (size_t)(t - 1) * BH, H3l + (size_t)(t - 1) * BH,
                     UaTh, UaTl, Hh, 2 * Hh, Hh };
            SegB a2{ ch, cl, UaTh + Hh, UaTl + Hh, Hh, 2 * Hh, Hh };
            if (t < Ss - 1)
                attn_fused_k<3, 1><<<agrid, 256, 0, stream>>>(
                    a0, a1, a2, VaTh, VaTl, sa_ba, X, t, xth, xtl, xsh, xsl);
            else
                attn_fused_k<3, 0><<<agrid, 256, 0, stream>>>(
                    a0, a1, a2, VaTh, VaTl, sa_ba, X, t, xth, xtl, xsh, xsl);
        }

        // gates + LSTM fused
        SegB g0{ xth, xtl, saWth, saWtl, Dd, Dd, Dd };
        if (t == 0) {
            gemm_gates_k<1, 1, 0><<<ggrid, 256, 0, stream>>>(
                g0, g0, sa_b, nullptr, nullptr, cbuf,
                H3h + (size_t)t * BH, H3l + (size_t)t * BH, ch, cl);
        } else {
            SegB g1{ H3h + (size_t)(t - 1) * BH, H3l + (size_t)(t - 1) * BH,
                     saUth, saUtl, Hh, Hh, Hh };
            gemm_gates_k<2, 0, 0><<<ggrid, 256, 0, stream>>>(
                g0, g1, sa_b, nullptr, nullptr, cbuf,
                H3h + (size_t)t * BH, H3l + (size_t)t * BH, ch, cl);
        }
    }

    // ---- temporal attention: beta (MFMA+fused finish), then h_ctx in place ----
    beta_k<<<dim3((Ss * Bb) / 128), 256, 0, stream>>>(
        H3h, H3l, tWaTh, tWaTl, ta_ba, ta_Va, beta);
    hctx_all_k<<<Bb, 256, 0, stream>>>(H3h, H3l, beta);

    // ---- temporal LSTM (H3 planes now hold h_ctx); lh ping-pong ----
    for (int t = 0; t < Ss; ++t) {
        SegB g0{ H3h + (size_t)t * BH, H3l + (size_t)t * BH,
                 taWth, taWtl, Hh, Hh, Hh };
        const int po = t & 1;
        if (t == 0) {
            gemm_gates_k<1, 1, 1><<<ggrid, 256, 0, stream>>>(
                g0, g0, ta_b, ta_Wy, yv, lc, lhh[0], lhl[0], nullptr, nullptr);
        } else {
            SegB g1{ lhh[(t - 1) & 1], lhl[(t - 1) & 1], taUth, taUtl, Hh, Hh, Hh };
            gemm_gates_k<2, 0, 1><<<ggrid, 256, 0, stream>>>(
                g0, g1, ta_b, ta_Wy, yv, lc, lhh[po], lhl[po], nullptr, nullptr);
        }
        y_k<<<Bb, 256, 0, stream>>>(lhh[po], lhl[po], fc_W, fc_b, yv,
                                    (t == Ss - 1) ? (float*)d_out : nullptr);
    }
}

// Round 9
// 2400.170 us; speedup vs baseline: 1.2542x; 1.2542x over previous
//
#include <hip/hip_runtime.h>

// STA-LSTM forward. B=4096 S=16 D=256 HS=HT=512. Output y (B,1) fp32.
// R9 = R7 revert + ONE surgical fusion.
//   R8 lesson: direct global->VGPR frag loads at 4 waves/CU are latency-
//   murdered (80 us/step, VALUBusy 5%). LDS-staged + barrier is the proven
//   structure; keep it everywhere.
//   New: a2sm_k = A2 GEMM (tmp@Va, B staged per-chunk like gates) + softmax
//   + xt-split + X[:,t+1]-split in one kernel. A-frags prefetched for all
//   8 chunks upfront. Kills 16 softmax dispatches + av HBM round-trip.
//   A1 (32x64 staged), gates (m97 plateau), beta, hctx, y unchanged from R7.
// ws: ~184 MiB.

constexpr int Bb = 4096;
constexpr int Ss = 16;
constexpr int Dd = 256;
constexpr int Hh = 512;   // HS == HT

typedef __attribute__((ext_vector_type(8))) short short8;
typedef __attribute__((ext_vector_type(4))) float f32x4;

__device__ __forceinline__ float sigm(float x) { return 1.0f / (1.0f + expf(-x)); }

__device__ __forceinline__ unsigned short f2bf(float x) {   // RNE fp32->bf16 bits
    unsigned int u = __float_as_uint(x);
    u = (u + 0x7fffu + ((u >> 16) & 1u)) >> 16;
    return (unsigned short)u;
}
__device__ __forceinline__ float bf2f(unsigned short h) {
    return __uint_as_float(((unsigned int)h) << 16);
}
__device__ __forceinline__ void async16(const void* g, void* l) {
    __builtin_amdgcn_global_load_lds(
        (const __attribute__((address_space(1))) void*)g,
        (__attribute__((address_space(3))) void*)l, 16, 0, 0);
}
__device__ __forceinline__ short8 ldg8(const unsigned short* p) {
    return *reinterpret_cast<const short8*>(p);
}

struct SegB { const unsigned short* Ah; const unsigned short* Al;
              const unsigned short* Bh; const unsigned short* Bl;
              int lda; int ldb; int K; };

// ================= generic split-bf16 MFMA GEMM (A1) ==========
// C[M,N] = sum_seg (Ah+Al)[M,K] @ (Bh+Bl)[N,K]^T, dropping Al*Bl.
// EPI=1: v=tanh(acc+bias[col]); split-store to Th/Tl.
template<int BM, int BN, int NSEG, int EPI>
__global__ __launch_bounds__(256) void gemm_mfma_k(
    SegB s0, SegB s1, SegB s2,
    const float* __restrict__ bias,
    float* __restrict__ C,
    unsigned short* __restrict__ Th, unsigned short* __restrict__ Tl,
    int ldc)
{
    constexpr int WM = BM / 2, WN = BN / 2;
    constexpr int FI = WM / 16, FJ = WN / 16;
    __shared__ __align__(16) unsigned short sA[2][BM * 32];
    __shared__ __align__(16) unsigned short sB[2][BN * 32];
    const int tid  = threadIdx.x;
    const int lane = tid & 63;
    const int wv   = tid >> 6;
    const int wm   = wv & 1, wn = wv >> 1;
    const int row0 = blockIdx.x * BM;
    const int col0 = blockIdx.y * BN;

    f32x4 acc[FI][FJ];
#pragma unroll
    for (int i = 0; i < FI; i++)
#pragma unroll
        for (int j = 0; j < FJ; j++) acc[i][j] = (f32x4){0.f, 0.f, 0.f, 0.f};

    const int lrow = lane >> 2;
    const int lcol = (lane & 3) * 8;
    const int q8   = (lane >> 4) * 8;
    const int l15  = lane & 15;

#pragma unroll
    for (int sgi = 0; sgi < NSEG; ++sgi) {
        const SegB sg = (sgi == 0) ? s0 : ((sgi == 1) ? s1 : s2);
        const int K = sg.K;
        for (int k0 = 0; k0 < K; k0 += 32) {
#pragma unroll
            for (int c = wv; c < BM / 16; c += 4) {
                const int r = c * 16 + lrow;
                const size_t gA = (size_t)(row0 + r) * sg.lda + k0 + lcol;
                const int lo = c * 512 + lane * 8;
                async16(sg.Ah + gA, &sA[0][lo]);
                async16(sg.Al + gA, &sA[1][lo]);
            }
#pragma unroll
            for (int c = wv; c < BN / 16; c += 4) {
                const int r = c * 16 + lrow;
                const size_t gB = (size_t)(col0 + r) * sg.ldb + k0 + lcol;
                const int lo = c * 512 + lane * 8;
                async16(sg.Bh + gB, &sB[0][lo]);
                async16(sg.Bl + gB, &sB[1][lo]);
            }
            __syncthreads();
            short8 ah[FI], al[FI], bh[FJ], bl[FJ];
#pragma unroll
            for (int i = 0; i < FI; i++) {
                const int m = wm * WM + i * 16 + l15;
                ah[i] = *reinterpret_cast<const short8*>(&sA[0][m * 32 + q8]);
                al[i] = *reinterpret_cast<const short8*>(&sA[1][m * 32 + q8]);
            }
#pragma unroll
            for (int j = 0; j < FJ; j++) {
                const int n = wn * WN + j * 16 + l15;
                bh[j] = *reinterpret_cast<const short8*>(&sB[0][n * 32 + q8]);
                bl[j] = *reinterpret_cast<const short8*>(&sB[1][n * 32 + q8]);
            }
#pragma unroll
            for (int i = 0; i < FI; i++)
#pragma unroll
                for (int j = 0; j < FJ; j++) {
                    acc[i][j] = __builtin_amdgcn_mfma_f32_16x16x32_bf16(ah[i], bh[j], acc[i][j], 0, 0, 0);
                    acc[i][j] = __builtin_amdgcn_mfma_f32_16x16x32_bf16(ah[i], bl[j], acc[i][j], 0, 0, 0);
                    acc[i][j] = __builtin_amdgcn_mfma_f32_16x16x32_bf16(al[i], bh[j], acc[i][j], 0, 0, 0);
                }
            __syncthreads();
        }
    }
#pragma unroll
    for (int i = 0; i < FI; i++) {
#pragma unroll
        for (int j = 0; j < FJ; j++) {
            const int col = col0 + wn * WN + j * 16 + l15;
#pragma unroll
            for (int r = 0; r < 4; r++) {
                const int row = row0 + wm * WM + i * 16 + (lane >> 4) * 4 + r;
                float v = acc[i][j][r];
                if (EPI == 1) {
                    v = tanhf(v + bias[col]);
                    unsigned short hb = f2bf(v);
                    Th[(size_t)row * ldc + col] = hb;
                    Tl[(size_t)row * ldc + col] = f2bf(v - bf2f(hb));
                } else {
                    C[(size_t)row * ldc + col] = v;
                }
            }
        }
    }
}

// ======= a2sm: av = tmp @ VaT^T, then softmax + xt split (+X[t+1] split) ====
// Block = 16 rows x N=256, 4 waves (wave owns 64 cols). B staged per-chunk
// into LDS (gates pattern); A-frags prefetched for all 8 chunks upfront.
template<int SPLITX>
__global__ __launch_bounds__(256) void a2sm_k(
    const unsigned short* __restrict__ tmph, const unsigned short* __restrict__ tmpl,
    const unsigned short* __restrict__ VaTh, const unsigned short* __restrict__ VaTl,
    const float* __restrict__ X, int t,
    unsigned short* __restrict__ xth, unsigned short* __restrict__ xtl,
    unsigned short* __restrict__ xsh, unsigned short* __restrict__ xsl)
{
    __shared__ __align__(16) unsigned short sB[2][256 * 32];  // 32 KB
    __shared__ __align__(16) float av[16 * 260];               // 16.6 KB
    __shared__ float rpart[16][16];
    __shared__ float spart[16][16];

    const int tid  = threadIdx.x;
    const int lane = tid & 63;
    const int wv   = tid >> 6;
    const int q8   = (lane >> 4) * 8;
    const int l15  = lane & 15;
    const int quad = lane >> 4;
    const int lrow = lane >> 2;
    const int lcol = (lane & 3) * 8;
    const int row0 = blockIdx.x * 16;

    // prefetch A-frags for all 8 k-chunks (latency hidden behind staging)
    short8 a_h[8], a_l[8];
#pragma unroll
    for (int kc = 0; kc < 8; kc++) {
        const size_t aoff = (size_t)(row0 + l15) * 256 + kc * 32 + q8;
        a_h[kc] = ldg8(tmph + aoff);
        a_l[kc] = ldg8(tmpl + aoff);
    }

    f32x4 acc[4];
#pragma unroll
    for (int j = 0; j < 4; j++) acc[j] = (f32x4){0.f, 0.f, 0.f, 0.f};

    for (int kc = 0; kc < 8; ++kc) {
        const int k0 = kc * 32;
#pragma unroll
        for (int c = wv; c < 16; c += 4) {
            const int n = c * 16 + lrow;
            const size_t gB = (size_t)n * 256 + k0 + lcol;
            const int lo = c * 512 + lane * 8;
            async16(VaTh + gB, &sB[0][lo]);
            async16(VaTl + gB, &sB[1][lo]);
        }
        __syncthreads();
#pragma unroll
        for (int j = 0; j < 4; j++) {
            const int n = wv * 64 + j * 16 + l15;
            const short8 b_h = *reinterpret_cast<const short8*>(&sB[0][n * 32 + q8]);
            const short8 b_l = *reinterpret_cast<const short8*>(&sB[1][n * 32 + q8]);
            acc[j] = __builtin_amdgcn_mfma_f32_16x16x32_bf16(a_h[kc], b_h, acc[j], 0, 0, 0);
            acc[j] = __builtin_amdgcn_mfma_f32_16x16x32_bf16(a_h[kc], b_l, acc[j], 0, 0, 0);
            acc[j] = __builtin_amdgcn_mfma_f32_16x16x32_bf16(a_l[kc], b_h, acc[j], 0, 0, 0);
        }
        __syncthreads();
    }

    // av (C layout: col=lane&15, row=quad*4+r)
#pragma unroll
    for (int j = 0; j < 4; j++) {
        const int col = wv * 64 + j * 16 + l15;
#pragma unroll
        for (int r = 0; r < 4; r++) av[(quad * 4 + r) * 260 + col] = acc[j][r];
    }
    __syncthreads();

    // softmax over 256 + scale by x_t (+ split X[:,t+1])
    const int row = tid >> 4;
    const int sl  = tid & 15;
    const int c0  = sl * 16;
    float* avr = av + row * 260;
    float mx = avr[c0];
#pragma unroll
    for (int i = 1; i < 16; i++) mx = fmaxf(mx, avr[c0 + i]);
    rpart[row][sl] = mx;
    __syncthreads();
    float M = rpart[row][0];
#pragma unroll
    for (int i = 1; i < 16; i++) M = fmaxf(M, rpart[row][i]);
    float s = 0.0f;
#pragma unroll
    for (int i = 0; i < 16; i++) {
        const float e = expf(avr[c0 + i] - M);
        avr[c0 + i] = e;
        s += e;
    }
    spart[row][sl] = s;
    __syncthreads();
    float S = spart[row][0];
#pragma unroll
    for (int i = 1; i < 16; i++) S += spart[row][i];
    const float inv = 1.0f / S;

    const size_t b = (size_t)(row0 + row);
    const float* Xr = X + b * (Ss * Dd) + (size_t)t * Dd + c0;
    unsigned short* xhp = xth + b * Dd + c0;
    unsigned short* xlp = xtl + b * Dd + c0;
#pragma unroll
    for (int g = 0; g < 4; g++) {
        const float4 xv = *reinterpret_cast<const float4*>(Xr + g * 4);
        const float v0 = avr[c0 + g * 4 + 0] * inv * xv.x;
        const float v1 = avr[c0 + g * 4 + 1] * inv * xv.y;
        const float v2 = avr[c0 + g * 4 + 2] * inv * xv.z;
        const float v3 = avr[c0 + g * 4 + 3] * inv * xv.w;
        ushort4 ho, lo;
        ho.x = f2bf(v0); lo.x = f2bf(v0 - bf2f(ho.x));
        ho.y = f2bf(v1); lo.y = f2bf(v1 - bf2f(ho.y));
        ho.z = f2bf(v2); lo.z = f2bf(v2 - bf2f(ho.z));
        ho.w = f2bf(v3); lo.w = f2bf(v3 - bf2f(ho.w));
        *reinterpret_cast<ushort4*>(xhp + g * 4) = ho;
        *reinterpret_cast<ushort4*>(xlp + g * 4) = lo;
    }
    if (SPLITX) {
        const float* Xn = X + b * (Ss * Dd) + (size_t)(t + 1) * Dd + c0;
        unsigned short* shp = xsh + b * Dd + c0;
        unsigned short* slp = xsl + b * Dd + c0;
#pragma unroll
        for (int g = 0; g < 4; g++) {
            const float4 xv = *reinterpret_cast<const float4*>(Xn + g * 4);
            ushort4 ho, lo;
            ho.x = f2bf(xv.x); lo.x = f2bf(xv.x - bf2f(ho.x));
            ho.y = f2bf(xv.y); lo.y = f2bf(xv.y - bf2f(ho.y));
            ho.z = f2bf(xv.z); lo.z = f2bf(xv.z - bf2f(ho.z));
            ho.w = f2bf(xv.w); lo.w = f2bf(xv.w - bf2f(ho.w));
            *reinterpret_cast<ushort4*>(shp + g * 4) = ho;
            *reinterpret_cast<ushort4*>(slp + g * 4) = lo;
        }
    }
}

// ============ fused gates GEMM + LSTM pointwise (unchanged from R7) ========
template<int NSEG, int ZC, int TA>
__global__ __launch_bounds__(256) void gemm_gates_k(
    SegB s0, SegB s1,
    const float* __restrict__ bias,
    const float* __restrict__ wy,
    const float* __restrict__ yv,
    float* __restrict__ c_io,
    unsigned short* __restrict__ hh, unsigned short* __restrict__ hl,
    unsigned short* __restrict__ ch, unsigned short* __restrict__ cl)
{
    __shared__ __align__(16) unsigned short sA[2][128 * 32];
    __shared__ __align__(16) unsigned short sB[2][128 * 32];
    const int tid  = threadIdx.x;
    const int lane = tid & 63;
    const int wv   = tid >> 6;
    const int wm   = wv & 1, wn = wv >> 1;
    const int row0 = blockIdx.x * 128;
    const int by32 = blockIdx.y * 32;

    f32x4 acc[4][4];   // [m-tile][gate]
#pragma unroll
    for (int i = 0; i < 4; i++)
#pragma unroll
        for (int g = 0; g < 4; g++) acc[i][g] = (f32x4){0.f, 0.f, 0.f, 0.f};

    const int lrow = lane >> 2;
    const int lcol = (lane & 3) * 8;
    const int q8   = (lane >> 4) * 8;
    const int l15  = lane & 15;

#pragma unroll
    for (int sgi = 0; sgi < NSEG; ++sgi) {
        const SegB sg = (sgi == 0) ? s0 : s1;
        const int K = sg.K;
        for (int k0 = 0; k0 < K; k0 += 32) {
#pragma unroll
            for (int c = wv; c < 8; c += 4) {
                const int r = c * 16 + lrow;
                const size_t gA = (size_t)(row0 + r) * sg.lda + k0 + lcol;
                const int lo = c * 512 + lane * 8;
                async16(sg.Ah + gA, &sA[0][lo]);
                async16(sg.Al + gA, &sA[1][lo]);
            }
#pragma unroll
            for (int cc = wv; cc < 8; cc += 4) {
                const int g  = cc >> 1;
                const int jj = (cc & 1) * 16 + lrow;
                const int rowg = g * 512 + by32 + jj;
                const size_t gB = (size_t)rowg * sg.ldb + k0 + lcol;
                const int lo = cc * 512 + lane * 8;
                async16(sg.Bh + gB, &sB[0][lo]);
                async16(sg.Bl + gB, &sB[1][lo]);
            }
            __syncthreads();
            short8 ah[4], al[4], bh[4], bl[4];
#pragma unroll
            for (int i = 0; i < 4; i++) {
                const int m = wm * 64 + i * 16 + l15;
                ah[i] = *reinterpret_cast<const short8*>(&sA[0][m * 32 + q8]);
                al[i] = *reinterpret_cast<const short8*>(&sA[1][m * 32 + q8]);
            }
#pragma unroll
            for (int g = 0; g < 4; g++) {
                const int n = g * 32 + wn * 16 + l15;
                bh[g] = *reinterpret_cast<const short8*>(&sB[0][n * 32 + q8]);
                bl[g] = *reinterpret_cast<const short8*>(&sB[1][n * 32 + q8]);
            }
#pragma unroll
            for (int i = 0; i < 4; i++)
#pragma unroll
                for (int g = 0; g < 4; g++) {
                    acc[i][g] = __builtin_amdgcn_mfma_f32_16x16x32_bf16(ah[i], bh[g], acc[i][g], 0, 0, 0);
                    acc[i][g] = __builtin_amdgcn_mfma_f32_16x16x32_bf16(ah[i], bl[g], acc[i][g], 0, 0, 0);
                    acc[i][g] = __builtin_amdgcn_mfma_f32_16x16x32_bf16(al[i], bh[g], acc[i][g], 0, 0, 0);
                }
            __syncthreads();
        }
    }
    // ---- fused LSTM epilogue ----
    const int j = by32 + wn * 16 + l15;          // 0..511
    const float b0 = bias[j],            b1 = bias[Hh + j];
    const float b2 = bias[2 * Hh + j],   b3 = bias[3 * Hh + j];
    float w0 = 0.f, w1 = 0.f, w2 = 0.f, w3 = 0.f;
    if (TA) { w0 = wy[j]; w1 = wy[Hh + j]; w2 = wy[2 * Hh + j]; w3 = wy[3 * Hh + j]; }
#pragma unroll
    for (int i = 0; i < 4; i++) {
        const int rbase = row0 + wm * 64 + i * 16 + (lane >> 4) * 4;
#pragma unroll
        for (int r = 0; r < 4; r++) {
            const int row = rbase + r;
            float gi = acc[i][0][r] + b0;
            float gf = acc[i][1][r] + b1;
            float gg = acc[i][2][r] + b2;
            float go = acc[i][3][r] + b3;
            if (TA) {
                const float yb = yv[row];
                gi += yb * w0; gf += yb * w1; gg += yb * w2; go += yb * w3;
            }
            const float i_ = sigm(gi), f_ = sigm(gf), gv = tanhf(gg), o_ = sigm(go);
            const size_t idx = (size_t)row * Hh + j;
            const float cp = ZC ? 0.0f : c_io[idx];
            const float c = f_ * cp + i_ * gv;
            c_io[idx] = c;
            const float h = o_ * tanhf(c);
            const unsigned short hb = f2bf(h);
            hh[idx] = hb;
            hl[idx] = f2bf(h - bf2f(hb));
            if (!TA) {
                const unsigned short cb = f2bf(c);
                ch[idx] = cb;
                cl[idx] = f2bf(c - bf2f(cb));
            }
        }
    }
}

// ============ weight prep: W[K][N] fp32 -> Th,Tl [N][K] bf16 ============
__global__ __launch_bounds__(256) void splitT_k(const float* __restrict__ W,
                                                unsigned short* __restrict__ Th,
                                                unsigned short* __restrict__ Tl,
                                                int Kd, int Nd)
{
    __shared__ float tile[32][33];
    const int bk = blockIdx.x * 32, bn = blockIdx.y * 32;
    const int tid = threadIdx.x;
    const int r = tid >> 3, c4 = (tid & 7) * 4;
    const float4 v = *reinterpret_cast<const float4*>(&W[(size_t)(bk + r) * Nd + bn + c4]);
    tile[r][c4 + 0] = v.x; tile[r][c4 + 1] = v.y;
    tile[r][c4 + 2] = v.z; tile[r][c4 + 3] = v.w;
    __syncthreads();
    const int n = r, k4 = c4;
    ushort4 hq, lq;
    unsigned short* hp = (unsigned short*)&hq;
    unsigned short* lp = (unsigned short*)&lq;
#pragma unroll
    for (int q = 0; q < 4; q++) {
        float x = tile[k4 + q][n];
        unsigned short h = f2bf(x);
        hp[q] = h;
        lp[q] = f2bf(x - bf2f(h));
    }
    *reinterpret_cast<ushort4*>(&Th[(size_t)(bn + n) * Kd + bk + k4]) = hq;
    *reinterpret_cast<ushort4*>(&Tl[(size_t)(bn + n) * Kd + bk + k4]) = lq;
}

// ---- ta_Wa [512][16] -> WaT hi/lo [16][512] ----
__global__ __launch_bounds__(256) void splitWa_k(const float* __restrict__ W,
                                                 unsigned short* __restrict__ Th,
                                                 unsigned short* __restrict__ Tl)
{
    int idx = blockIdx.x * 256 + threadIdx.x;   // 8192
    int n = idx >> 9, k = idx & 511;
    float x = W[(size_t)k * 16 + n];
    unsigned short h = f2bf(x);
    Th[idx] = h;
    Tl[idx] = f2bf(x - bf2f(h));
}

// -------- init: y0 = X[:,0,255]; split X[:,0,:] --------
__global__ __launch_bounds__(256) void init_k(const float* __restrict__ X,
                                              unsigned short* __restrict__ xsh,
                                              unsigned short* __restrict__ xsl,
                                              float* __restrict__ yv)
{
    int idx = blockIdx.x * 256 + threadIdx.x;
    int b = idx >> 8, d = idx & 255;
    float xv = X[(size_t)b * (Ss * Dd) + d];
    unsigned short hb = f2bf(xv);
    xsh[idx] = hb;
    xsl[idx] = f2bf(xv - bf2f(hb));
    if (d == Dd - 1) yv[b] = xv;
}

// ------- beta: MFMA logits (65536x512 @ WaT 16x512) + fused tanh/@Va/softmax -------
__global__ __launch_bounds__(256) void beta_k(const unsigned short* __restrict__ H3h,
                                              const unsigned short* __restrict__ H3l,
                                              const unsigned short* __restrict__ WaTh,
                                              const unsigned short* __restrict__ WaTl,
                                              const float* __restrict__ taba,
                                              const float* __restrict__ taVa,
                                              float* __restrict__ beta)
{
    __shared__ __align__(16) unsigned short sW[2][16 * 512];   // 32 KB
    __shared__ __align__(16) unsigned short sA[2][128 * 32];   // 16 KB
    __shared__ float tt[128][17];                               // 8.5 KB
    __shared__ float Vas[256];
    const int tid  = threadIdx.x;
    const int lane = tid & 63;
    const int wv   = tid >> 6;
    const int lrow = lane >> 2;
    const int lcol = (lane & 3) * 8;
    const int q8   = (lane >> 4) * 8;
    const int l15  = lane & 15;
    const size_t row0 = (size_t)blockIdx.x * 128;

#pragma unroll
    for (int it = 0; it < 4; ++it) {
        const int lo = wv * 2048 + it * 512 + lane * 8;
        async16(WaTh + lo, &sW[0][lo]);
        async16(WaTl + lo, &sW[1][lo]);
    }
    Vas[tid] = taVa[tid];

    f32x4 acc[2];
    acc[0] = (f32x4){0.f, 0.f, 0.f, 0.f};
    acc[1] = (f32x4){0.f, 0.f, 0.f, 0.f};

    for (int kc = 0; kc < 16; ++kc) {
        const int k0 = kc * 32;
#pragma unroll
        for (int c = wv; c < 8; c += 4) {
            const int r = c * 16 + lrow;
            const size_t gA = (row0 + r) * Hh + k0 + lcol;
            const int lo = c * 512 + lane * 8;
            async16(H3h + gA, &sA[0][lo]);
            async16(H3l + gA, &sA[1][lo]);
        }
        __syncthreads();
        const short8 bh = *reinterpret_cast<const short8*>(&sW[0][l15 * 512 + k0 + q8]);
        const short8 bl = *reinterpret_cast<const short8*>(&sW[1][l15 * 512 + k0 + q8]);
#pragma unroll
        for (int i = 0; i < 2; i++) {
            const int m = wv * 32 + i * 16 + l15;
            const short8 ah = *reinterpret_cast<const short8*>(&sA[0][m * 32 + q8]);
            const short8 al = *reinterpret_cast<const short8*>(&sA[1][m * 32 + q8]);
            acc[i] = __builtin_amdgcn_mfma_f32_16x16x32_bf16(ah, bh, acc[i], 0, 0, 0);
            acc[i] = __builtin_amdgcn_mfma_f32_16x16x32_bf16(ah, bl, acc[i], 0, 0, 0);
            acc[i] = __builtin_amdgcn_mfma_f32_16x16x32_bf16(al, bh, acc[i], 0, 0, 0);
        }
        __syncthreads();
    }
    const float ba = taba[l15];
#pragma unroll
    for (int i = 0; i < 2; i++) {
#pragma unroll
        for (int r = 0; r < 4; r++) {
            const int rl = wv * 32 + i * 16 + (lane >> 4) * 4 + r;
            tt[rl][l15] = tanhf(acc[i][r] + ba);
        }
    }
    __syncthreads();
    if (tid < 128) {
        float tv[16];
#pragma unroll
        for (int m = 0; m < 16; m++) tv[m] = tt[tid][m];
        float l[16];
        float mx = -1e30f;
#pragma unroll
        for (int n = 0; n < 16; n++) {
            float s = 0.0f;
#pragma unroll
            for (int m = 0; m < 16; m++) s = fmaf(tv[m], Vas[m * 16 + n], s);
            l[n] = s;
            mx = fmaxf(mx, s);
        }
        float sum = 0.0f;
#pragma unroll
        for (int n = 0; n < 16; n++) { l[n] = expf(l[n] - mx); sum += l[n]; }
        const float inv = 1.0f / sum;
        float* bp = beta + (row0 + tid) * 16;
#pragma unroll
        for (int n4 = 0; n4 < 4; n4++) {
            float4 v = { l[n4 * 4] * inv, l[n4 * 4 + 1] * inv,
                         l[n4 * 4 + 2] * inv, l[n4 * 4 + 3] * inv };
            *reinterpret_cast<float4*>(bp + n4 * 4) = v;
        }
    }
}

// ------- h_ctx for ALL t in one dispatch, in-place into H3 (vectorized) -------
__global__ __launch_bounds__(256) void hctx_all_k(unsigned short* __restrict__ H3h,
                                                  unsigned short* __restrict__ H3l,
                                                  const float* __restrict__ beta)
{
    const int b = blockIdx.x, tid = threadIdx.x;
    __shared__ float4 Hs4[16][129];   // 16 s x 128 quads (+1 pad)
    __shared__ float bs[16][16];
    for (int i = tid; i < 16 * 128; i += 256) {
        const int s = i >> 7, q = i & 127;
        const size_t o = ((size_t)s * Bb + b) * Hh + q * 4;
        const ushort4 hv = *reinterpret_cast<const ushort4*>(&H3h[o]);
        const ushort4 lv = *reinterpret_cast<const ushort4*>(&H3l[o]);
        Hs4[s][q] = (float4){ bf2f(hv.x) + bf2f(lv.x), bf2f(hv.y) + bf2f(lv.y),
                              bf2f(hv.z) + bf2f(lv.z), bf2f(hv.w) + bf2f(lv.w) };
    }
    {
        const int t = tid >> 4, s = tid & 15;
        bs[t][s] = beta[((size_t)t * Bb + b) * 16 + s];
    }
    __syncthreads();
    const int q  = tid & 127;
    const int t0 = tid >> 7;          // 0 or 1
#pragma unroll
    for (int tt = 0; tt < 8; tt++) {
        const int t = tt * 2 + t0;
        float4 a = (float4){0.f, 0.f, 0.f, 0.f};
#pragma unroll
        for (int s = 0; s < 16; s++) {
            const float w = bs[t][s];
            const float4 hv = Hs4[s][q];
            a.x = fmaf(w, hv.x, a.x); a.y = fmaf(w, hv.y, a.y);
            a.z = fmaf(w, hv.z, a.z); a.w = fmaf(w, hv.w, a.w);
        }
        ushort4 ho, lo;
        ho.x = f2bf(a.x); lo.x = f2bf(a.x - bf2f(ho.x));
        ho.y = f2bf(a.y); lo.y = f2bf(a.y - bf2f(ho.y));
        ho.z = f2bf(a.z); lo.z = f2bf(a.z - bf2f(ho.z));
        ho.w = f2bf(a.w); lo.w = f2bf(a.w - bf2f(ho.w));
        const size_t o = ((size_t)t * Bb + b) * Hh + q * 4;
        *reinterpret_cast<ushort4*>(&H3h[o]) = ho;
        *reinterpret_cast<ushort4*>(&H3l[o]) = lo;
    }
}

// ---------------- y = lh @ fc_W.T + fc_b (lh from hi/lo) ----------------
__global__ __launch_bounds__(256) void y_k(const unsigned short* __restrict__ hh,
                                           const unsigned short* __restrict__ hl,
                                           const float* __restrict__ fcW,
                                           const float* __restrict__ fcb,
                                           float* __restrict__ yv,
                                           float* __restrict__ outp)
{
    int b = blockIdx.x, tid = threadIdx.x;
    size_t o = (size_t)b * Hh + tid;
    float h0 = bf2f(hh[o]) + bf2f(hl[o]);
    float h1 = bf2f(hh[o + 256]) + bf2f(hl[o + 256]);
    float p = h0 * fcW[tid] + h1 * fcW[tid + 256];
#pragma unroll
    for (int off = 32; off > 0; off >>= 1) p += __shfl_down(p, off, 64);
    __shared__ float wred[4];
    if ((tid & 63) == 0) wred[tid >> 6] = p;
    __syncthreads();
    if (tid == 0) {
        float y = fcb[0] + wred[0] + wred[1] + wred[2] + wred[3];
        yv[b] = y;
        if (outp) outp[b] = y;
    }
}

extern "C" void kernel_launch(void* const* d_in, const int* in_sizes, int n_in,
                              void* d_out, int out_size, void* d_ws, size_t ws_size,
                              hipStream_t stream)
{
    (void)in_sizes; (void)n_in; (void)out_size; (void)ws_size;
    const float* X     = (const float*)d_in[0];
    const float* sa_W  = (const float*)d_in[1];
    const float* sa_U  = (const float*)d_in[2];
    const float* sa_b  = (const float*)d_in[3];
    const float* sa_Wa = (const float*)d_in[4];
    const float* sa_Ua = (const float*)d_in[5];
    const float* sa_ba = (const float*)d_in[6];
    const float* sa_Va = (const float*)d_in[7];
    const float* ta_Wa = (const float*)d_in[8];
    // d_in[9] = ta_Ua : multiplied by s0 == 0 -> unused
    const float* ta_ba = (const float*)d_in[10];
    const float* ta_Va = (const float*)d_in[11];
    const float* ta_W  = (const float*)d_in[12];
    const float* ta_U  = (const float*)d_in[13];
    const float* ta_b  = (const float*)d_in[14];
    const float* ta_Wy = (const float*)d_in[15];
    const float* fc_W  = (const float*)d_in[16];
    const float* fc_b  = (const float*)d_in[17];

    char* base = (char*)d_ws;
    size_t off = 0;
    auto alloc = [&](size_t bytes) {
        void* p = base + off; off += (bytes + 255) & ~(size_t)255; return p;
    };
    const size_t BH = (size_t)Bb * Hh;          // 2M elems
    unsigned short* H3h = (unsigned short*)alloc((size_t)Ss * BH * 2);  // 64 MiB
    unsigned short* H3l = (unsigned short*)alloc((size_t)Ss * BH * 2);  // 64 MiB
    float* cbuf = (float*)alloc(BH * 4);         // 8 MiB (sa c fp32; ta: lhA alias)
    float* lc   = (float*)alloc(BH * 4);         // 8 MiB
    unsigned short* lhBh = (unsigned short*)alloc(BH * 2);              // 4 MiB
    unsigned short* lhBl = (unsigned short*)alloc(BH * 2);              // 4 MiB
    unsigned short* xth = (unsigned short*)alloc((size_t)Bb * Dd * 2);  // 2 MiB
    unsigned short* xtl = (unsigned short*)alloc((size_t)Bb * Dd * 2);  // 2 MiB
    unsigned short* xsh = (unsigned short*)alloc((size_t)Bb * Dd * 2);  // 2 MiB
    unsigned short* xsl = (unsigned short*)alloc((size_t)Bb * Dd * 2);  // 2 MiB
    unsigned short* ch  = (unsigned short*)alloc(BH * 2);               // 4 MiB
    unsigned short* cl  = (unsigned short*)alloc(BH * 2);               // 4 MiB
    unsigned short* tmph = (unsigned short*)alloc((size_t)Bb * Dd * 2); // 2 MiB
    unsigned short* tmpl = (unsigned short*)alloc((size_t)Bb * Dd * 2); // 2 MiB
    unsigned short* saWth = (unsigned short*)alloc((size_t)Dd * 4 * Hh * 2);
    unsigned short* saWtl = (unsigned short*)alloc((size_t)Dd * 4 * Hh * 2);
    unsigned short* saUth = (unsigned short*)alloc((size_t)Hh * 4 * Hh * 2);
    unsigned short* saUtl = (unsigned short*)alloc((size_t)Hh * 4 * Hh * 2);
    unsigned short* taWth = (unsigned short*)alloc((size_t)Hh * 4 * Hh * 2);
    unsigned short* taWtl = (unsigned short*)alloc((size_t)Hh * 4 * Hh * 2);
    unsigned short* taUth = (unsigned short*)alloc((size_t)Hh * 4 * Hh * 2);
    unsigned short* taUtl = (unsigned short*)alloc((size_t)Hh * 4 * Hh * 2);
    unsigned short* WaTh = (unsigned short*)alloc((size_t)Dd * Dd * 2);
    unsigned short* WaTl = (unsigned short*)alloc((size_t)Dd * Dd * 2);
    unsigned short* UaTh = (unsigned short*)alloc((size_t)2 * Hh * Dd * 2);
    unsigned short* UaTl = (unsigned short*)alloc((size_t)2 * Hh * Dd * 2);
    unsigned short* VaTh = (unsigned short*)alloc((size_t)Dd * Dd * 2);
    unsigned short* VaTl = (unsigned short*)alloc((size_t)Dd * Dd * 2);
    unsigned short* tWaTh = (unsigned short*)alloc((size_t)16 * Hh * 2);
    unsigned short* tWaTl = (unsigned short*)alloc((size_t)16 * Hh * 2);
    float* yv = (float*)alloc((size_t)Bb * 4);
    // aliases (dead at time of reuse):
    float* beta = (float*)xth;                    // 4 MiB over xth+xtl (ta phase)
    unsigned short* lhAh = (unsigned short*)cbuf; // ta phase (cbuf dead)
    unsigned short* lhAl = (unsigned short*)cbuf + BH;
    unsigned short* lhh[2] = { lhAh, lhBh };
    unsigned short* lhl[2] = { lhAl, lhBl };
    // total ~184 MiB

    // ---- weight prep ----
    splitT_k<<<dim3(Dd / 32, (4 * Hh) / 32), 256, 0, stream>>>(sa_W, saWth, saWtl, Dd, 4 * Hh);
    splitT_k<<<dim3(Hh / 32, (4 * Hh) / 32), 256, 0, stream>>>(sa_U, saUth, saUtl, Hh, 4 * Hh);
    splitT_k<<<dim3(Hh / 32, (4 * Hh) / 32), 256, 0, stream>>>(ta_W, taWth, taWtl, Hh, 4 * Hh);
    splitT_k<<<dim3(Hh / 32, (4 * Hh) / 32), 256, 0, stream>>>(ta_U, taUth, taUtl, Hh, 4 * Hh);
    splitT_k<<<dim3(Dd / 32, Dd / 32), 256, 0, stream>>>(sa_Wa, WaTh, WaTl, Dd, Dd);
    splitT_k<<<dim3((2 * Hh) / 32, Dd / 32), 256, 0, stream>>>(sa_Ua, UaTh, UaTl, 2 * Hh, Dd);
    splitT_k<<<dim3(Dd / 32, Dd / 32), 256, 0, stream>>>(sa_Va, VaTh, VaTl, Dd, Dd);
    splitWa_k<<<dim3(32), 256, 0, stream>>>(ta_Wa, tWaTh, tWaTl);
    init_k<<<dim3((Bb * Dd) / 256), 256, 0, stream>>>(X, xsh, xsl, yv);

    const dim3 agrid(Bb / 32, Dd / 64);          // 128 x 4 = 512 blocks
    const dim3 smgrid(Bb / 16);                  // 256 blocks
    const dim3 ggrid(Bb / 128, Hh / 32);         // 32 x 16

    // ---- spatial-attention LSTM ----
    for (int t = 0; t < Ss; ++t) {
        // tmp = tanh(x_t @ sa_Wa + h @ Ua[:HS] + c @ Ua[HS:] + sa_ba) [MFMA]
        SegB a0{ xsh, xsl, WaTh, WaTl, Dd, Dd, Dd };
        if (t == 0) {
            gemm_mfma_k<32, 64, 1, 1><<<agrid, 256, 0, stream>>>(
                a0, a0, a0, sa_ba, nullptr, tmph, tmpl, Dd);
        } else {
            SegB a1{ H3h + (size_t)(t - 1) * BH, H3l + (size_t)(t - 1) * BH,
                     UaTh, UaTl, Hh, 2 * Hh, Hh };
            SegB a2{ ch, cl, UaTh + Hh, UaTl + Hh, Hh, 2 * Hh, Hh };
            gemm_mfma_k<32, 64, 3, 1><<<agrid, 256, 0, stream>>>(
                a0, a1, a2, sa_ba, nullptr, tmph, tmpl, Dd);
        }

        // av = tmp @ sa_Va, softmax, xt split, X[:,t+1] split  [fused]
        if (t < Ss - 1)
            a2sm_k<1><<<smgrid, 256, 0, stream>>>(
                tmph, tmpl, VaTh, VaTl, X, t, xth, xtl, xsh, xsl);
        else
            a2sm_k<0><<<smgrid, 256, 0, stream>>>(
                tmph, tmpl, VaTh, VaTl, X, t, xth, xtl, xsh, xsl);

        // gates + LSTM fused
        SegB g0{ xth, xtl, saWth, saWtl, Dd, Dd, Dd };
        if (t == 0) {
            gemm_gates_k<1, 1, 0><<<ggrid, 256, 0, stream>>>(
                g0, g0, sa_b, nullptr, nullptr, cbuf,
                H3h + (size_t)t * BH, H3l + (size_t)t * BH, ch, cl);
        } else {
            SegB g1{ H3h + (size_t)(t - 1) * BH, H3l + (size_t)(t - 1) * BH,
                     saUth, saUtl, Hh, Hh, Hh };
            gemm_gates_k<2, 0, 0><<<ggrid, 256, 0, stream>>>(
                g0, g1, sa_b, nullptr, nullptr, cbuf,
                H3h + (size_t)t * BH, H3l + (size_t)t * BH, ch, cl);
        }
    }

    // ---- temporal attention: beta (MFMA+fused finish), then h_ctx in place ----
    beta_k<<<dim3((Ss * Bb) / 128), 256, 0, stream>>>(
        H3h, H3l, tWaTh, tWaTl, ta_ba, ta_Va, beta);
    hctx_all_k<<<Bb, 256, 0, stream>>>(H3h, H3l, beta);

    // ---- temporal LSTM (H3 planes now hold h_ctx); lh ping-pong ----
    for (int t = 0; t < Ss; ++t) {
        SegB g0{ H3h + (size_t)t * BH, H3l + (size_t)t * BH,
                 taWth, taWtl, Hh, Hh, Hh };
        const int po = t & 1;
        if (t == 0) {
            gemm_gates_k<1, 1, 1><<<ggrid, 256, 0, stream>>>(
                g0, g0, ta_b, ta_Wy, yv, lc, lhh[0], lhl[0], nullptr, nullptr);
        } else {
            SegB g1{ lhh[(t - 1) & 1], lhl[(t - 1) & 1], taUth, taUtl, Hh, Hh, Hh };
            gemm_gates_k<2, 0, 1><<<ggrid, 256, 0, stream>>>(
                g0, g1, ta_b, ta_Wy, yv, lc, lhh[po], lhl[po], nullptr, nullptr);
        }
        y_k<<<Bb, 256, 0, stream>>>(lhh[po], lhl[po], fc_W, fc_b, yv,
                                    (t == Ss - 1) ? (float*)d_out : nullptr);
    }
}

// Round 10
// 2383.330 us; speedup vs baseline: 1.2631x; 1.0071x over previous
//
#include <hip/hip_runtime.h>

// STA-LSTM forward. B=4096 S=16 D=256 HS=HT=512. Output y (B,1) fp32.
// R10 (on R9):
//   - A1: 32x64 -> 32x32 tiles (grid 1024 = 4 blocks/CU; A1 was barrier-
//     latency bound at 2/CU: ~825 cyc/chunk vs ~120 cyc of work).
//   - hctx_all_k: register-accumulator rewrite. Thread owns 2 h-elems,
//     all 16 s-values in 32 VGPRs; LDS only for the 16x16 beta table
//     (broadcast reads, free). R9's float4-LDS had 8-way bank aliasing
//     (16B lane stride) -> 5.2e6 conflicts; this has zero LDS data traffic.
//   Gates (m97 plateau), a2sm, beta, y, precision scheme unchanged.
// ws: ~184 MiB.

constexpr int Bb = 4096;
constexpr int Ss = 16;
constexpr int Dd = 256;
constexpr int Hh = 512;   // HS == HT

typedef __attribute__((ext_vector_type(8))) short short8;
typedef __attribute__((ext_vector_type(4))) float f32x4;

__device__ __forceinline__ float sigm(float x) { return 1.0f / (1.0f + expf(-x)); }

__device__ __forceinline__ unsigned short f2bf(float x) {   // RNE fp32->bf16 bits
    unsigned int u = __float_as_uint(x);
    u = (u + 0x7fffu + ((u >> 16) & 1u)) >> 16;
    return (unsigned short)u;
}
__device__ __forceinline__ float bf2f(unsigned short h) {
    return __uint_as_float(((unsigned int)h) << 16);
}
__device__ __forceinline__ void async16(const void* g, void* l) {
    __builtin_amdgcn_global_load_lds(
        (const __attribute__((address_space(1))) void*)g,
        (__attribute__((address_space(3))) void*)l, 16, 0, 0);
}
__device__ __forceinline__ short8 ldg8(const unsigned short* p) {
    return *reinterpret_cast<const short8*>(p);
}

struct SegB { const unsigned short* Ah; const unsigned short* Al;
              const unsigned short* Bh; const unsigned short* Bl;
              int lda; int ldb; int K; };

// ================= generic split-bf16 MFMA GEMM (A1) ==========
template<int BM, int BN, int NSEG, int EPI>
__global__ __launch_bounds__(256) void gemm_mfma_k(
    SegB s0, SegB s1, SegB s2,
    const float* __restrict__ bias,
    float* __restrict__ C,
    unsigned short* __restrict__ Th, unsigned short* __restrict__ Tl,
    int ldc)
{
    constexpr int WM = BM / 2, WN = BN / 2;
    constexpr int FI = WM / 16, FJ = WN / 16;
    __shared__ __align__(16) unsigned short sA[2][BM * 32];
    __shared__ __align__(16) unsigned short sB[2][BN * 32];
    const int tid  = threadIdx.x;
    const int lane = tid & 63;
    const int wv   = tid >> 6;
    const int wm   = wv & 1, wn = wv >> 1;
    const int row0 = blockIdx.x * BM;
    const int col0 = blockIdx.y * BN;

    f32x4 acc[FI][FJ];
#pragma unroll
    for (int i = 0; i < FI; i++)
#pragma unroll
        for (int j = 0; j < FJ; j++) acc[i][j] = (f32x4){0.f, 0.f, 0.f, 0.f};

    const int lrow = lane >> 2;
    const int lcol = (lane & 3) * 8;
    const int q8   = (lane >> 4) * 8;
    const int l15  = lane & 15;

#pragma unroll
    for (int sgi = 0; sgi < NSEG; ++sgi) {
        const SegB sg = (sgi == 0) ? s0 : ((sgi == 1) ? s1 : s2);
        const int K = sg.K;
        for (int k0 = 0; k0 < K; k0 += 32) {
#pragma unroll
            for (int c = wv; c < BM / 16; c += 4) {
                const int r = c * 16 + lrow;
                const size_t gA = (size_t)(row0 + r) * sg.lda + k0 + lcol;
                const int lo = c * 512 + lane * 8;
                async16(sg.Ah + gA, &sA[0][lo]);
                async16(sg.Al + gA, &sA[1][lo]);
            }
#pragma unroll
            for (int c = wv; c < BN / 16; c += 4) {
                const int r = c * 16 + lrow;
                const size_t gB = (size_t)(col0 + r) * sg.ldb + k0 + lcol;
                const int lo = c * 512 + lane * 8;
                async16(sg.Bh + gB, &sB[0][lo]);
                async16(sg.Bl + gB, &sB[1][lo]);
            }
            __syncthreads();
            short8 ah[FI], al[FI], bh[FJ], bl[FJ];
#pragma unroll
            for (int i = 0; i < FI; i++) {
                const int m = wm * WM + i * 16 + l15;
                ah[i] = *reinterpret_cast<const short8*>(&sA[0][m * 32 + q8]);
                al[i] = *reinterpret_cast<const short8*>(&sA[1][m * 32 + q8]);
            }
#pragma unroll
            for (int j = 0; j < FJ; j++) {
                const int n = wn * WN + j * 16 + l15;
                bh[j] = *reinterpret_cast<const short8*>(&sB[0][n * 32 + q8]);
                bl[j] = *reinterpret_cast<const short8*>(&sB[1][n * 32 + q8]);
            }
#pragma unroll
            for (int i = 0; i < FI; i++)
#pragma unroll
                for (int j = 0; j < FJ; j++) {
                    acc[i][j] = __builtin_amdgcn_mfma_f32_16x16x32_bf16(ah[i], bh[j], acc[i][j], 0, 0, 0);
                    acc[i][j] = __builtin_amdgcn_mfma_f32_16x16x32_bf16(ah[i], bl[j], acc[i][j], 0, 0, 0);
                    acc[i][j] = __builtin_amdgcn_mfma_f32_16x16x32_bf16(al[i], bh[j], acc[i][j], 0, 0, 0);
                }
            __syncthreads();
        }
    }
#pragma unroll
    for (int i = 0; i < FI; i++) {
#pragma unroll
        for (int j = 0; j < FJ; j++) {
            const int col = col0 + wn * WN + j * 16 + l15;
#pragma unroll
            for (int r = 0; r < 4; r++) {
                const int row = row0 + wm * WM + i * 16 + (lane >> 4) * 4 + r;
                float v = acc[i][j][r];
                if (EPI == 1) {
                    v = tanhf(v + bias[col]);
                    unsigned short hb = f2bf(v);
                    Th[(size_t)row * ldc + col] = hb;
                    Tl[(size_t)row * ldc + col] = f2bf(v - bf2f(hb));
                } else {
                    C[(size_t)row * ldc + col] = v;
                }
            }
        }
    }
}

// ======= a2sm: av = tmp @ VaT^T, then softmax + xt split (+X[t+1] split) ====
template<int SPLITX>
__global__ __launch_bounds__(256) void a2sm_k(
    const unsigned short* __restrict__ tmph, const unsigned short* __restrict__ tmpl,
    const unsigned short* __restrict__ VaTh, const unsigned short* __restrict__ VaTl,
    const float* __restrict__ X, int t,
    unsigned short* __restrict__ xth, unsigned short* __restrict__ xtl,
    unsigned short* __restrict__ xsh, unsigned short* __restrict__ xsl)
{
    __shared__ __align__(16) unsigned short sB[2][256 * 32];  // 32 KB
    __shared__ __align__(16) float av[16 * 260];               // 16.6 KB
    __shared__ float rpart[16][16];
    __shared__ float spart[16][16];

    const int tid  = threadIdx.x;
    const int lane = tid & 63;
    const int wv   = tid >> 6;
    const int q8   = (lane >> 4) * 8;
    const int l15  = lane & 15;
    const int quad = lane >> 4;
    const int lrow = lane >> 2;
    const int lcol = (lane & 3) * 8;
    const int row0 = blockIdx.x * 16;

    short8 a_h[8], a_l[8];
#pragma unroll
    for (int kc = 0; kc < 8; kc++) {
        const size_t aoff = (size_t)(row0 + l15) * 256 + kc * 32 + q8;
        a_h[kc] = ldg8(tmph + aoff);
        a_l[kc] = ldg8(tmpl + aoff);
    }

    f32x4 acc[4];
#pragma unroll
    for (int j = 0; j < 4; j++) acc[j] = (f32x4){0.f, 0.f, 0.f, 0.f};

    for (int kc = 0; kc < 8; ++kc) {
        const int k0 = kc * 32;
#pragma unroll
        for (int c = wv; c < 16; c += 4) {
            const int n = c * 16 + lrow;
            const size_t gB = (size_t)n * 256 + k0 + lcol;
            const int lo = c * 512 + lane * 8;
            async16(VaTh + gB, &sB[0][lo]);
            async16(VaTl + gB, &sB[1][lo]);
        }
        __syncthreads();
#pragma unroll
        for (int j = 0; j < 4; j++) {
            const int n = wv * 64 + j * 16 + l15;
            const short8 b_h = *reinterpret_cast<const short8*>(&sB[0][n * 32 + q8]);
            const short8 b_l = *reinterpret_cast<const short8*>(&sB[1][n * 32 + q8]);
            acc[j] = __builtin_amdgcn_mfma_f32_16x16x32_bf16(a_h[kc], b_h, acc[j], 0, 0, 0);
            acc[j] = __builtin_amdgcn_mfma_f32_16x16x32_bf16(a_h[kc], b_l, acc[j], 0, 0, 0);
            acc[j] = __builtin_amdgcn_mfma_f32_16x16x32_bf16(a_l[kc], b_h, acc[j], 0, 0, 0);
        }
        __syncthreads();
    }

#pragma unroll
    for (int j = 0; j < 4; j++) {
        const int col = wv * 64 + j * 16 + l15;
#pragma unroll
        for (int r = 0; r < 4; r++) av[(quad * 4 + r) * 260 + col] = acc[j][r];
    }
    __syncthreads();

    const int row = tid >> 4;
    const int sl  = tid & 15;
    const int c0  = sl * 16;
    float* avr = av + row * 260;
    float mx = avr[c0];
#pragma unroll
    for (int i = 1; i < 16; i++) mx = fmaxf(mx, avr[c0 + i]);
    rpart[row][sl] = mx;
    __syncthreads();
    float M = rpart[row][0];
#pragma unroll
    for (int i = 1; i < 16; i++) M = fmaxf(M, rpart[row][i]);
    float s = 0.0f;
#pragma unroll
    for (int i = 0; i < 16; i++) {
        const float e = expf(avr[c0 + i] - M);
        avr[c0 + i] = e;
        s += e;
    }
    spart[row][sl] = s;
    __syncthreads();
    float S = spart[row][0];
#pragma unroll
    for (int i = 1; i < 16; i++) S += spart[row][i];
    const float inv = 1.0f / S;

    const size_t b = (size_t)(row0 + row);
    const float* Xr = X + b * (Ss * Dd) + (size_t)t * Dd + c0;
    unsigned short* xhp = xth + b * Dd + c0;
    unsigned short* xlp = xtl + b * Dd + c0;
#pragma unroll
    for (int g = 0; g < 4; g++) {
        const float4 xv = *reinterpret_cast<const float4*>(Xr + g * 4);
        const float v0 = avr[c0 + g * 4 + 0] * inv * xv.x;
        const float v1 = avr[c0 + g * 4 + 1] * inv * xv.y;
        const float v2 = avr[c0 + g * 4 + 2] * inv * xv.z;
        const float v3 = avr[c0 + g * 4 + 3] * inv * xv.w;
        ushort4 ho, lo;
        ho.x = f2bf(v0); lo.x = f2bf(v0 - bf2f(ho.x));
        ho.y = f2bf(v1); lo.y = f2bf(v1 - bf2f(ho.y));
        ho.z = f2bf(v2); lo.z = f2bf(v2 - bf2f(ho.z));
        ho.w = f2bf(v3); lo.w = f2bf(v3 - bf2f(ho.w));
        *reinterpret_cast<ushort4*>(xhp + g * 4) = ho;
        *reinterpret_cast<ushort4*>(xlp + g * 4) = lo;
    }
    if (SPLITX) {
        const float* Xn = X + b * (Ss * Dd) + (size_t)(t + 1) * Dd + c0;
        unsigned short* shp = xsh + b * Dd + c0;
        unsigned short* slp = xsl + b * Dd + c0;
#pragma unroll
        for (int g = 0; g < 4; g++) {
            const float4 xv = *reinterpret_cast<const float4*>(Xn + g * 4);
            ushort4 ho, lo;
            ho.x = f2bf(xv.x); lo.x = f2bf(xv.x - bf2f(ho.x));
            ho.y = f2bf(xv.y); lo.y = f2bf(xv.y - bf2f(ho.y));
            ho.z = f2bf(xv.z); lo.z = f2bf(xv.z - bf2f(ho.z));
            ho.w = f2bf(xv.w); lo.w = f2bf(xv.w - bf2f(ho.w));
            *reinterpret_cast<ushort4*>(shp + g * 4) = ho;
            *reinterpret_cast<ushort4*>(slp + g * 4) = lo;
        }
    }
}

// ============ fused gates GEMM + LSTM pointwise (unchanged) ========
template<int NSEG, int ZC, int TA>
__global__ __launch_bounds__(256) void gemm_gates_k(
    SegB s0, SegB s1,
    const float* __restrict__ bias,
    const float* __restrict__ wy,
    const float* __restrict__ yv,
    float* __restrict__ c_io,
    unsigned short* __restrict__ hh, unsigned short* __restrict__ hl,
    unsigned short* __restrict__ ch, unsigned short* __restrict__ cl)
{
    __shared__ __align__(16) unsigned short sA[2][128 * 32];
    __shared__ __align__(16) unsigned short sB[2][128 * 32];
    const int tid  = threadIdx.x;
    const int lane = tid & 63;
    const int wv   = tid >> 6;
    const int wm   = wv & 1, wn = wv >> 1;
    const int row0 = blockIdx.x * 128;
    const int by32 = blockIdx.y * 32;

    f32x4 acc[4][4];   // [m-tile][gate]
#pragma unroll
    for (int i = 0; i < 4; i++)
#pragma unroll
        for (int g = 0; g < 4; g++) acc[i][g] = (f32x4){0.f, 0.f, 0.f, 0.f};

    const int lrow = lane >> 2;
    const int lcol = (lane & 3) * 8;
    const int q8   = (lane >> 4) * 8;
    const int l15  = lane & 15;

#pragma unroll
    for (int sgi = 0; sgi < NSEG; ++sgi) {
        const SegB sg = (sgi == 0) ? s0 : s1;
        const int K = sg.K;
        for (int k0 = 0; k0 < K; k0 += 32) {
#pragma unroll
            for (int c = wv; c < 8; c += 4) {
                const int r = c * 16 + lrow;
                const size_t gA = (size_t)(row0 + r) * sg.lda + k0 + lcol;
                const int lo = c * 512 + lane * 8;
                async16(sg.Ah + gA, &sA[0][lo]);
                async16(sg.Al + gA, &sA[1][lo]);
            }
#pragma unroll
            for (int cc = wv; cc < 8; cc += 4) {
                const int g  = cc >> 1;
                const int jj = (cc & 1) * 16 + lrow;
                const int rowg = g * 512 + by32 + jj;
                const size_t gB = (size_t)rowg * sg.ldb + k0 + lcol;
                const int lo = cc * 512 + lane * 8;
                async16(sg.Bh + gB, &sB[0][lo]);
                async16(sg.Bl + gB, &sB[1][lo]);
            }
            __syncthreads();
            short8 ah[4], al[4], bh[4], bl[4];
#pragma unroll
            for (int i = 0; i < 4; i++) {
                const int m = wm * 64 + i * 16 + l15;
                ah[i] = *reinterpret_cast<const short8*>(&sA[0][m * 32 + q8]);
                al[i] = *reinterpret_cast<const short8*>(&sA[1][m * 32 + q8]);
            }
#pragma unroll
            for (int g = 0; g < 4; g++) {
                const int n = g * 32 + wn * 16 + l15;
                bh[g] = *reinterpret_cast<const short8*>(&sB[0][n * 32 + q8]);
                bl[g] = *reinterpret_cast<const short8*>(&sB[1][n * 32 + q8]);
            }
#pragma unroll
            for (int i = 0; i < 4; i++)
#pragma unroll
                for (int g = 0; g < 4; g++) {
                    acc[i][g] = __builtin_amdgcn_mfma_f32_16x16x32_bf16(ah[i], bh[g], acc[i][g], 0, 0, 0);
                    acc[i][g] = __builtin_amdgcn_mfma_f32_16x16x32_bf16(ah[i], bl[g], acc[i][g], 0, 0, 0);
                    acc[i][g] = __builtin_amdgcn_mfma_f32_16x16x32_bf16(al[i], bh[g], acc[i][g], 0, 0, 0);
                }
            __syncthreads();
        }
    }
    // ---- fused LSTM epilogue ----
    const int j = by32 + wn * 16 + l15;          // 0..511
    const float b0 = bias[j],            b1 = bias[Hh + j];
    const float b2 = bias[2 * Hh + j],   b3 = bias[3 * Hh + j];
    float w0 = 0.f, w1 = 0.f, w2 = 0.f, w3 = 0.f;
    if (TA) { w0 = wy[j]; w1 = wy[Hh + j]; w2 = wy[2 * Hh + j]; w3 = wy[3 * Hh + j]; }
#pragma unroll
    for (int i = 0; i < 4; i++) {
        const int rbase = row0 + wm * 64 + i * 16 + (lane >> 4) * 4;
#pragma unroll
        for (int r = 0; r < 4; r++) {
            const int row = rbase + r;
            float gi = acc[i][0][r] + b0;
            float gf = acc[i][1][r] + b1;
            float gg = acc[i][2][r] + b2;
            float go = acc[i][3][r] + b3;
            if (TA) {
                const float yb = yv[row];
                gi += yb * w0; gf += yb * w1; gg += yb * w2; go += yb * w3;
            }
            const float i_ = sigm(gi), f_ = sigm(gf), gv = tanhf(gg), o_ = sigm(go);
            const size_t idx = (size_t)row * Hh + j;
            const float cp = ZC ? 0.0f : c_io[idx];
            const float c = f_ * cp + i_ * gv;
            c_io[idx] = c;
            const float h = o_ * tanhf(c);
            const unsigned short hb = f2bf(h);
            hh[idx] = hb;
            hl[idx] = f2bf(h - bf2f(hb));
            if (!TA) {
                const unsigned short cb = f2bf(c);
                ch[idx] = cb;
                cl[idx] = f2bf(c - bf2f(cb));
            }
        }
    }
}

// ============ weight prep: W[K][N] fp32 -> Th,Tl [N][K] bf16 ============
__global__ __launch_bounds__(256) void splitT_k(const float* __restrict__ W,
                                                unsigned short* __restrict__ Th,
                                                unsigned short* __restrict__ Tl,
                                                int Kd, int Nd)
{
    __shared__ float tile[32][33];
    const int bk = blockIdx.x * 32, bn = blockIdx.y * 32;
    const int tid = threadIdx.x;
    const int r = tid >> 3, c4 = (tid & 7) * 4;
    const float4 v = *reinterpret_cast<const float4*>(&W[(size_t)(bk + r) * Nd + bn + c4]);
    tile[r][c4 + 0] = v.x; tile[r][c4 + 1] = v.y;
    tile[r][c4 + 2] = v.z; tile[r][c4 + 3] = v.w;
    __syncthreads();
    const int n = r, k4 = c4;
    ushort4 hq, lq;
    unsigned short* hp = (unsigned short*)&hq;
    unsigned short* lp = (unsigned short*)&lq;
#pragma unroll
    for (int q = 0; q < 4; q++) {
        float x = tile[k4 + q][n];
        unsigned short h = f2bf(x);
        hp[q] = h;
        lp[q] = f2bf(x - bf2f(h));
    }
    *reinterpret_cast<ushort4*>(&Th[(size_t)(bn + n) * Kd + bk + k4]) = hq;
    *reinterpret_cast<ushort4*>(&Tl[(size_t)(bn + n) * Kd + bk + k4]) = lq;
}

// ---- ta_Wa [512][16] -> WaT hi/lo [16][512] ----
__global__ __launch_bounds__(256) void splitWa_k(const float* __restrict__ W,
                                                 unsigned short* __restrict__ Th,
                                                 unsigned short* __restrict__ Tl)
{
    int idx = blockIdx.x * 256 + threadIdx.x;   // 8192
    int n = idx >> 9, k = idx & 511;
    float x = W[(size_t)k * 16 + n];
    unsigned short h = f2bf(x);
    Th[idx] = h;
    Tl[idx] = f2bf(x - bf2f(h));
}

// -------- init: y0 = X[:,0,255]; split X[:,0,:] --------
__global__ __launch_bounds__(256) void init_k(const float* __restrict__ X,
                                              unsigned short* __restrict__ xsh,
                                              unsigned short* __restrict__ xsl,
                                              float* __restrict__ yv)
{
    int idx = blockIdx.x * 256 + threadIdx.x;
    int b = idx >> 8, d = idx & 255;
    float xv = X[(size_t)b * (Ss * Dd) + d];
    unsigned short hb = f2bf(xv);
    xsh[idx] = hb;
    xsl[idx] = f2bf(xv - bf2f(hb));
    if (d == Dd - 1) yv[b] = xv;
}

// ------- beta: MFMA logits + fused tanh/@Va/softmax (unchanged) -------
__global__ __launch_bounds__(256) void beta_k(const unsigned short* __restrict__ H3h,
                                              const unsigned short* __restrict__ H3l,
                                              const unsigned short* __restrict__ WaTh,
                                              const unsigned short* __restrict__ WaTl,
                                              const float* __restrict__ taba,
                                              const float* __restrict__ taVa,
                                              float* __restrict__ beta)
{
    __shared__ __align__(16) unsigned short sW[2][16 * 512];   // 32 KB
    __shared__ __align__(16) unsigned short sA[2][128 * 32];   // 16 KB
    __shared__ float tt[128][17];                               // 8.5 KB
    __shared__ float Vas[256];
    const int tid  = threadIdx.x;
    const int lane = tid & 63;
    const int wv   = tid >> 6;
    const int lrow = lane >> 2;
    const int lcol = (lane & 3) * 8;
    const int q8   = (lane >> 4) * 8;
    const int l15  = lane & 15;
    const size_t row0 = (size_t)blockIdx.x * 128;

#pragma unroll
    for (int it = 0; it < 4; ++it) {
        const int lo = wv * 2048 + it * 512 + lane * 8;
        async16(WaTh + lo, &sW[0][lo]);
        async16(WaTl + lo, &sW[1][lo]);
    }
    Vas[tid] = taVa[tid];

    f32x4 acc[2];
    acc[0] = (f32x4){0.f, 0.f, 0.f, 0.f};
    acc[1] = (f32x4){0.f, 0.f, 0.f, 0.f};

    for (int kc = 0; kc < 16; ++kc) {
        const int k0 = kc * 32;
#pragma unroll
        for (int c = wv; c < 8; c += 4) {
            const int r = c * 16 + lrow;
            const size_t gA = (row0 + r) * Hh + k0 + lcol;
            const int lo = c * 512 + lane * 8;
            async16(H3h + gA, &sA[0][lo]);
            async16(H3l + gA, &sA[1][lo]);
        }
        __syncthreads();
        const short8 bh = *reinterpret_cast<const short8*>(&sW[0][l15 * 512 + k0 + q8]);
        const short8 bl = *reinterpret_cast<const short8*>(&sW[1][l15 * 512 + k0 + q8]);
#pragma unroll
        for (int i = 0; i < 2; i++) {
            const int m = wv * 32 + i * 16 + l15;
            const short8 ah = *reinterpret_cast<const short8*>(&sA[0][m * 32 + q8]);
            const short8 al = *reinterpret_cast<const short8*>(&sA[1][m * 32 + q8]);
            acc[i] = __builtin_amdgcn_mfma_f32_16x16x32_bf16(ah, bh, acc[i], 0, 0, 0);
            acc[i] = __builtin_amdgcn_mfma_f32_16x16x32_bf16(ah, bl, acc[i], 0, 0, 0);
            acc[i] = __builtin_amdgcn_mfma_f32_16x16x32_bf16(al, bh, acc[i], 0, 0, 0);
        }
        __syncthreads();
    }
    const float ba = taba[l15];
#pragma unroll
    for (int i = 0; i < 2; i++) {
#pragma unroll
        for (int r = 0; r < 4; r++) {
            const int rl = wv * 32 + i * 16 + (lane >> 4) * 4 + r;
            tt[rl][l15] = tanhf(acc[i][r] + ba);
        }
    }
    __syncthreads();
    if (tid < 128) {
        float tv[16];
#pragma unroll
        for (int m = 0; m < 16; m++) tv[m] = tt[tid][m];
        float l[16];
        float mx = -1e30f;
#pragma unroll
        for (int n = 0; n < 16; n++) {
            float s = 0.0f;
#pragma unroll
            for (int m = 0; m < 16; m++) s = fmaf(tv[m], Vas[m * 16 + n], s);
            l[n] = s;
            mx = fmaxf(mx, s);
        }
        float sum = 0.0f;
#pragma unroll
        for (int n = 0; n < 16; n++) { l[n] = expf(l[n] - mx); sum += l[n]; }
        const float inv = 1.0f / sum;
        float* bp = beta + (row0 + tid) * 16;
#pragma unroll
        for (int n4 = 0; n4 < 4; n4++) {
            float4 v = { l[n4 * 4] * inv, l[n4 * 4 + 1] * inv,
                         l[n4 * 4 + 2] * inv, l[n4 * 4 + 3] * inv };
            *reinterpret_cast<float4*>(bp + n4 * 4) = v;
        }
    }
}

// ------- h_ctx all t, in-place, register-accumulator version -------
// Thread owns h = {tid*2, tid*2+1}; all 16 s-values live in 32 VGPRs.
// LDS only holds the 16x16 beta table (broadcast reads). Writes touch only
// batch row b -> race-free.
__global__ __launch_bounds__(256) void hctx_all_k(unsigned short* __restrict__ H3h,
                                                  unsigned short* __restrict__ H3l,
                                                  const float* __restrict__ beta)
{
    const int b = blockIdx.x, tid = threadIdx.x;
    __shared__ float bs[16][16];
    {
        const int t = tid >> 4, s = tid & 15;
        bs[t][s] = beta[((size_t)t * Bb + b) * 16 + s];
    }
    float h0[16], h1[16];
    const int e0 = tid * 2;
#pragma unroll
    for (int s = 0; s < 16; s++) {
        const size_t o = ((size_t)s * Bb + b) * Hh + e0;
        const ushort2 hv = *reinterpret_cast<const ushort2*>(&H3h[o]);
        const ushort2 lv = *reinterpret_cast<const ushort2*>(&H3l[o]);
        h0[s] = bf2f(hv.x) + bf2f(lv.x);
        h1[s] = bf2f(hv.y) + bf2f(lv.y);
    }
    __syncthreads();
#pragma unroll
    for (int t = 0; t < 16; t++) {
        float a0 = 0.f, a1 = 0.f;
#pragma unroll
        for (int s = 0; s < 16; s++) {
            const float w = bs[t][s];
            a0 = fmaf(w, h0[s], a0);
            a1 = fmaf(w, h1[s], a1);
        }
        ushort2 ho, lo;
        ho.x = f2bf(a0); lo.x = f2bf(a0 - bf2f(ho.x));
        ho.y = f2bf(a1); lo.y = f2bf(a1 - bf2f(ho.y));
        const size_t o = ((size_t)t * Bb + b) * Hh + e0;
        *reinterpret_cast<ushort2*>(&H3h[o]) = ho;
        *reinterpret_cast<ushort2*>(&H3l[o]) = lo;
    }
}

// ---------------- y = lh @ fc_W.T + fc_b (lh from hi/lo) ----------------
__global__ __launch_bounds__(256) void y_k(const unsigned short* __restrict__ hh,
                                           const unsigned short* __restrict__ hl,
                                           const float* __restrict__ fcW,
                                           const float* __restrict__ fcb,
                                           float* __restrict__ yv,
                                           float* __restrict__ outp)
{
    int b = blockIdx.x, tid = threadIdx.x;
    size_t o = (size_t)b * Hh + tid;
    float h0 = bf2f(hh[o]) + bf2f(hl[o]);
    float h1 = bf2f(hh[o + 256]) + bf2f(hl[o + 256]);
    float p = h0 * fcW[tid] + h1 * fcW[tid + 256];
#pragma unroll
    for (int off = 32; off > 0; off >>= 1) p += __shfl_down(p, off, 64);
    __shared__ float wred[4];
    if ((tid & 63) == 0) wred[tid >> 6] = p;
    __syncthreads();
    if (tid == 0) {
        float y = fcb[0] + wred[0] + wred[1] + wred[2] + wred[3];
        yv[b] = y;
        if (outp) outp[b] = y;
    }
}

extern "C" void kernel_launch(void* const* d_in, const int* in_sizes, int n_in,
                              void* d_out, int out_size, void* d_ws, size_t ws_size,
                              hipStream_t stream)
{
    (void)in_sizes; (void)n_in; (void)out_size; (void)ws_size;
    const float* X     = (const float*)d_in[0];
    const float* sa_W  = (const float*)d_in[1];
    const float* sa_U  = (const float*)d_in[2];
    const float* sa_b  = (const float*)d_in[3];
    const float* sa_Wa = (const float*)d_in[4];
    const float* sa_Ua = (const float*)d_in[5];
    const float* sa_ba = (const float*)d_in[6];
    const float* sa_Va = (const float*)d_in[7];
    const float* ta_Wa = (const float*)d_in[8];
    // d_in[9] = ta_Ua : multiplied by s0 == 0 -> unused
    const float* ta_ba = (const float*)d_in[10];
    const float* ta_Va = (const float*)d_in[11];
    const float* ta_W  = (const float*)d_in[12];
    const float* ta_U  = (const float*)d_in[13];
    const float* ta_b  = (const float*)d_in[14];
    const float* ta_Wy = (const float*)d_in[15];
    const float* fc_W  = (const float*)d_in[16];
    const float* fc_b  = (const float*)d_in[17];

    char* base = (char*)d_ws;
    size_t off = 0;
    auto alloc = [&](size_t bytes) {
        void* p = base + off; off += (bytes + 255) & ~(size_t)255; return p;
    };
    const size_t BH = (size_t)Bb * Hh;          // 2M elems
    unsigned short* H3h = (unsigned short*)alloc((size_t)Ss * BH * 2);  // 64 MiB
    unsigned short* H3l = (unsigned short*)alloc((size_t)Ss * BH * 2);  // 64 MiB
    float* cbuf = (float*)alloc(BH * 4);         // 8 MiB (sa c fp32; ta: lhA alias)
    float* lc   = (float*)alloc(BH * 4);         // 8 MiB
    unsigned short* lhBh = (unsigned short*)alloc(BH * 2);              // 4 MiB
    unsigned short* lhBl = (unsigned short*)alloc(BH * 2);              // 4 MiB
    unsigned short* xth = (unsigned short*)alloc((size_t)Bb * Dd * 2);  // 2 MiB
    unsigned short* xtl = (unsigned short*)alloc((size_t)Bb * Dd * 2);  // 2 MiB
    unsigned short* xsh = (unsigned short*)alloc((size_t)Bb * Dd * 2);  // 2 MiB
    unsigned short* xsl = (unsigned short*)alloc((size_t)Bb * Dd * 2);  // 2 MiB
    unsigned short* ch  = (unsigned short*)alloc(BH * 2);               // 4 MiB
    unsigned short* cl  = (unsigned short*)alloc(BH * 2);               // 4 MiB
    unsigned short* tmph = (unsigned short*)alloc((size_t)Bb * Dd * 2); // 2 MiB
    unsigned short* tmpl = (unsigned short*)alloc((size_t)Bb * Dd * 2); // 2 MiB
    unsigned short* saWth = (unsigned short*)alloc((size_t)Dd * 4 * Hh * 2);
    unsigned short* saWtl = (unsigned short*)alloc((size_t)Dd * 4 * Hh * 2);
    unsigned short* saUth = (unsigned short*)alloc((size_t)Hh * 4 * Hh * 2);
    unsigned short* saUtl = (unsigned short*)alloc((size_t)Hh * 4 * Hh * 2);
    unsigned short* taWth = (unsigned short*)alloc((size_t)Hh * 4 * Hh * 2);
    unsigned short* taWtl = (unsigned short*)alloc((size_t)Hh * 4 * Hh * 2);
    unsigned short* taUth = (unsigned short*)alloc((size_t)Hh * 4 * Hh * 2);
    unsigned short* taUtl = (unsigned short*)alloc((size_t)Hh * 4 * Hh * 2);
    unsigned short* WaTh = (unsigned short*)alloc((size_t)Dd * Dd * 2);
    unsigned short* WaTl = (unsigned short*)alloc((size_t)Dd * Dd * 2);
    unsigned short* UaTh = (unsigned short*)alloc((size_t)2 * Hh * Dd * 2);
    unsigned short* UaTl = (unsigned short*)alloc((size_t)2 * Hh * Dd * 2);
    unsigned short* VaTh = (unsigned short*)alloc((size_t)Dd * Dd * 2);
    unsigned short* VaTl = (unsigned short*)alloc((size_t)Dd * Dd * 2);
    unsigned short* tWaTh = (unsigned short*)alloc((size_t)16 * Hh * 2);
    unsigned short* tWaTl = (unsigned short*)alloc((size_t)16 * Hh * 2);
    float* yv = (float*)alloc((size_t)Bb * 4);
    // aliases (dead at time of reuse):
    float* beta = (float*)xth;                    // 4 MiB over xth+xtl (ta phase)
    unsigned short* lhAh = (unsigned short*)cbuf; // ta phase (cbuf dead)
    unsigned short* lhAl = (unsigned short*)cbuf + BH;
    unsigned short* lhh[2] = { lhAh, lhBh };
    unsigned short* lhl[2] = { lhAl, lhBl };
    // total ~184 MiB

    // ---- weight prep ----
    splitT_k<<<dim3(Dd / 32, (4 * Hh) / 32), 256, 0, stream>>>(sa_W, saWth, saWtl, Dd, 4 * Hh);
    splitT_k<<<dim3(Hh / 32, (4 * Hh) / 32), 256, 0, stream>>>(sa_U, saUth, saUtl, Hh, 4 * Hh);
    splitT_k<<<dim3(Hh / 32, (4 * Hh) / 32), 256, 0, stream>>>(ta_W, taWth, taWtl, Hh, 4 * Hh);
    splitT_k<<<dim3(Hh / 32, (4 * Hh) / 32), 256, 0, stream>>>(ta_U, taUth, taUtl, Hh, 4 * Hh);
    splitT_k<<<dim3(Dd / 32, Dd / 32), 256, 0, stream>>>(sa_Wa, WaTh, WaTl, Dd, Dd);
    splitT_k<<<dim3((2 * Hh) / 32, Dd / 32), 256, 0, stream>>>(sa_Ua, UaTh, UaTl, 2 * Hh, Dd);
    splitT_k<<<dim3(Dd / 32, Dd / 32), 256, 0, stream>>>(sa_Va, VaTh, VaTl, Dd, Dd);
    splitWa_k<<<dim3(32), 256, 0, stream>>>(ta_Wa, tWaTh, tWaTl);
    init_k<<<dim3((Bb * Dd) / 256), 256, 0, stream>>>(X, xsh, xsl, yv);

    const dim3 agrid(Bb / 32, Dd / 32);          // 128 x 8 = 1024 blocks
    const dim3 smgrid(Bb / 16);                  // 256 blocks
    const dim3 ggrid(Bb / 128, Hh / 32);         // 32 x 16

    // ---- spatial-attention LSTM ----
    for (int t = 0; t < Ss; ++t) {
        // tmp = tanh(x_t @ sa_Wa + h @ Ua[:HS] + c @ Ua[HS:] + sa_ba) [MFMA]
        SegB a0{ xsh, xsl, WaTh, WaTl, Dd, Dd, Dd };
        if (t == 0) {
            gemm_mfma_k<32, 32, 1, 1><<<agrid, 256, 0, stream>>>(
                a0, a0, a0, sa_ba, nullptr, tmph, tmpl, Dd);
        } else {
            SegB a1{ H3h + (size_t)(t - 1) * BH, H3l + (size_t)(t - 1) * BH,
                     UaTh, UaTl, Hh, 2 * Hh, Hh };
            SegB a2{ ch, cl, UaTh + Hh, UaTl + Hh, Hh, 2 * Hh, Hh };
            gemm_mfma_k<32, 32, 3, 1><<<agrid, 256, 0, stream>>>(
                a0, a1, a2, sa_ba, nullptr, tmph, tmpl, Dd);
        }

        // av = tmp @ sa_Va, softmax, xt split, X[:,t+1] split  [fused]
        if (t < Ss - 1)
            a2sm_k<1><<<smgrid, 256, 0, stream>>>(
                tmph, tmpl, VaTh, VaTl, X, t, xth, xtl, xsh, xsl);
        else
            a2sm_k<0><<<smgrid, 256, 0, stream>>>(
                tmph, tmpl, VaTh, VaTl, X, t, xth, xtl, xsh, xsl);

        // gates + LSTM fused
        SegB g0{ xth, xtl, saWth, saWtl, Dd, Dd, Dd };
        if (t == 0) {
            gemm_gates_k<1, 1, 0><<<ggrid, 256, 0, stream>>>(
                g0, g0, sa_b, nullptr, nullptr, cbuf,
                H3h + (size_t)t * BH, H3l + (size_t)t * BH, ch, cl);
        } else {
            SegB g1{ H3h + (size_t)(t - 1) * BH, H3l + (size_t)(t - 1) * BH,
                     saUth, saUtl, Hh, Hh, Hh };
            gemm_gates_k<2, 0, 0><<<ggrid, 256, 0, stream>>>(
                g0, g1, sa_b, nullptr, nullptr, cbuf,
                H3h + (size_t)t * BH, H3l + (size_t)t * BH, ch, cl);
        }
    }

    // ---- temporal attention: beta (MFMA+fused finish), then h_ctx in place ----
    beta_k<<<dim3((Ss * Bb) / 128), 256, 0, stream>>>(
        H3h, H3l, tWaTh, tWaTl, ta_ba, ta_Va, beta);
    hctx_all_k<<<dim3(Bb), 256, 0, stream>>>(H3h, H3l, beta);

    // ---- temporal LSTM (H3 planes now hold h_ctx); lh ping-pong ----
    for (int t = 0; t < Ss; ++t) {
        SegB g0{ H3h + (size_t)t * BH, H3l + (size_t)t * BH,
                 taWth, taWtl, Hh, Hh, Hh };
        const int po = t & 1;
        if (t == 0) {
            gemm_gates_k<1, 1, 1><<<ggrid, 256, 0, stream>>>(
                g0, g0, ta_b, ta_Wy, yv, lc, lhh[0], lhl[0], nullptr, nullptr);
        } else {
            SegB g1{ lhh[(t - 1) & 1], lhl[(t - 1) & 1], taUth, taUtl, Hh, Hh, Hh };
            gemm_gates_k<2, 0, 1><<<ggrid, 256, 0, stream>>>(
                g0, g1, ta_b, ta_Wy, yv, lc, lhh[po], lhl[po], nullptr, nullptr);
        }
        y_k<<<Bb, 256, 0, stream>>>(lhh[po], lhl[po], fc_W, fc_b, yv,
                                    (t == Ss - 1) ? (float*)d_out : nullptr);
    }
}